// Round 11
// baseline (181.350 us; speedup 1.0000x reference)
//
#include <hip/hip_runtime.h>
#include <hip/hip_bf16.h>

#define N_NODES 50000
#define NUM_P   20000
#define D_DIM   128
#define ALPHA_  0.2f
#define EPS_    1e-12f
#define NT      16      // nodes per tile (50000 = 3125*16, 20000 = 1250*16)

typedef __attribute__((ext_vector_type(8))) short bf16x8;
typedef __attribute__((ext_vector_type(4))) float f32x4;

__device__ __forceinline__ float4 f4zero() { return make_float4(0.f, 0.f, 0.f, 0.f); }

__device__ __forceinline__ void scale4(float4& v, const float s) {
    v.x *= s; v.y *= s; v.z *= s; v.w *= s;
}

__device__ __forceinline__ short f2bf(float f) {
    __hip_bfloat16 h = __float2bfloat16(f);
    return *reinterpret_cast<short*>(&h);
}

__device__ __forceinline__ float bf2f(short u) {
    union { unsigned i; float f; } c;
    c.i = ((unsigned)(unsigned short)u) << 16;
    return c.f;
}

__device__ __forceinline__ short4 pack4(const float4 v) {
    short4 s;
    s.x = f2bf(v.x); s.y = f2bf(v.y); s.z = f2bf(v.z); s.w = f2bf(v.w);
    return s;
}

// ---------------------------------------------------------------------------
// Weight pre-transpose+cvt to bf16:
//   o[0..32768)        = W1^T  [128 col][256 k]
//   o[32768..65536)    = W2^T  [128 col][256 k]
//   o[65536..81920)    = Whis^T[128 col][128 k]
//   o[81920..114688)   = WT^T  [128 col][256 k]
// ---------------------------------------------------------------------------
__global__ __launch_bounds__(256)
void wcvt2_kernel(const float* __restrict__ W1, const float* __restrict__ W2,
                  const float* __restrict__ Whis, const float* __restrict__ WTm,
                  short* __restrict__ o)
{
    const int i = blockIdx.x * 256 + threadIdx.x;   // 0..114687
    float v;
    if (i < 65536) {
        const float* W = (i < 32768) ? W1 : W2;
        const int t = i & 32767;
        v = W[(size_t)(t & 255) * D_DIM + (t >> 8)];
    } else if (i < 81920) {
        const int t = i - 65536;
        v = Whis[(size_t)(t & 127) * D_DIM + (t >> 7)];
    } else {
        const int t = i - 81920;
        v = WTm[(size_t)(t & 255) * D_DIM + (t >> 8)];
    }
    o[i] = f2bf(v);
}

// fp32 -> bf16 mirror (element count multiple of 1024)
__global__ __launch_bounds__(256)
void fcvt_kernel(const float* __restrict__ in, short* __restrict__ o)
{
    const int i = blockIdx.x * 256 + threadIdx.x;
    const float4 v = reinterpret_cast<const float4*>(in)[i];
    reinterpret_cast<short4*>(o)[i] = pack4(v);
}

// ---------------------------------------------------------------------------
// Barrier-free gather: one node per 32-lane group, no LDS, max occupancy.
// Writes the MFMA-A tile [self | mean] bf16, XOR-swizzled, to A (global).
// grid = N_NODES*32/256 = 6250 blocks.
// ---------------------------------------------------------------------------
template<int K>
__global__ __launch_bounds__(256)
void gather_a(const short* __restrict__ src,   // bf16 [*,128]
              const int*   __restrict__ idx,
              short* __restrict__ A)           // [N/16][16][256] swizzled
{
    const int gid  = blockIdx.x * 256 + threadIdx.x;
    const int node = gid >> 5;
    const int l    = gid & 31;
    if (node >= N_NODES) return;

    const short4 s4 = reinterpret_cast<const short4*>(src + (size_t)node * D_DIM)[l];

    const int* ir = idx + (size_t)node * K;
    float4 a4 = f4zero();
    for (int k = 0; k < K; ++k) {
        const int r = ir[k];
        const short4 v4 = reinterpret_cast<const short4*>(src + (size_t)r * D_DIM)[l];
        a4.x += bf2f(v4.x); a4.y += bf2f(v4.y);
        a4.z += bf2f(v4.z); a4.w += bf2f(v4.w);
    }
    scale4(a4, 1.0f / (float)K);

    const int n    = node & (NT - 1);
    const int swzn = (n & 7) << 3;
    short* dst = A + (size_t)(node >> 4) * (NT * 256) + n * 256;
    *reinterpret_cast<short4*>(&dst[(l * 4) ^ swzn])         = s4;
    *reinterpret_cast<short4*>(&dst[(D_DIM + l * 4) ^ swzn]) = pack4(a4);
}

// ---------------------------------------------------------------------------
// Slim MFMA GEMM over the staged A tiles: y = A @ W^T, leaky, l2norm, write.
// grid = 3125 blocks of 256 (16 nodes each).
// ---------------------------------------------------------------------------
__global__ __launch_bounds__(256)
void sage_gemm(const short* __restrict__ A,      // staged swizzled tiles
               const short* __restrict__ WTg,    // [128][256] bf16 = W^T
               float* __restrict__ out0,
               short* __restrict__ outb,
               int nb_limit,
               float* __restrict__ out1)
{
    __shared__ float ys[NT * 132];
    __shared__ float rnorm[NT];

    const int tid  = threadIdx.x;
    const int base = blockIdx.x * NT;
    const short* At = A + (size_t)blockIdx.x * (NT * 256);

    const int w    = tid >> 6;
    const int l    = tid & 63;
    const int arow = l & 15;
    const int kg   = l >> 4;
    const int swz  = (arow & 7) << 3;
    const int colbase = w * 32;

    f32x4 acc0 = {0.f, 0.f, 0.f, 0.f};
    f32x4 acc1 = {0.f, 0.f, 0.f, 0.f};
    const short* b0 = WTg + (size_t)(colbase + arow) * 256 + kg * 8;
    const short* b1 = b0 + 16 * 256;

    #pragma unroll
    for (int step = 0; step < 8; ++step) {
        const bf16x8 av  = *reinterpret_cast<const bf16x8*>(At + arow * 256 + ((step * 32 + kg * 8) ^ swz));
        const bf16x8 bv0 = *reinterpret_cast<const bf16x8*>(b0 + step * 32);
        const bf16x8 bv1 = *reinterpret_cast<const bf16x8*>(b1 + step * 32);
        acc0 = __builtin_amdgcn_mfma_f32_16x16x32_bf16(av, bv0, acc0, 0, 0, 0);
        acc1 = __builtin_amdgcn_mfma_f32_16x16x32_bf16(av, bv1, acc1, 0, 0, 0);
    }

    // epilogue: leaky -> ys (D layout: node=(l>>4)*4+r, col-local=l&15)
    {
        const int r0 = kg * 4;
        #pragma unroll
        for (int r = 0; r < 4; ++r) {
            float v0 = acc0[r]; v0 = v0 > 0.f ? v0 : ALPHA_ * v0;
            float v1 = acc1[r]; v1 = v1 > 0.f ? v1 : ALPHA_ * v1;
            ys[(r0 + r) * 132 + colbase + arow]      = v0;
            ys[(r0 + r) * 132 + colbase + 16 + arow] = v1;
        }
    }
    __syncthreads();

    {
        const int n  = tid >> 4;
        const int ll = tid & 15;
        float s = 0.f;
        #pragma unroll
        for (int jj = 0; jj < D_DIM; jj += 16) { const float t = ys[n * 132 + ll + jj]; s += t * t; }
        #pragma unroll
        for (int o = 8; o > 0; o >>= 1) s += __shfl_xor(s, o);
        if (ll == 0) rnorm[n] = 1.0f / fmaxf(sqrtf(s), EPS_);
    }
    __syncthreads();

    {
        const int j = tid & 127;
        const int g = tid >> 7;
        #pragma unroll
        for (int r = 0; r < 8; ++r) {
            const int n    = g * 8 + r;
            const int node = base + n;
            const float v  = ys[n * 132 + j] * rnorm[n];
            out0[(size_t)node * D_DIM + j] = v;
            if (outb != nullptr && node < nb_limit) outb[(size_t)node * D_DIM + j] = f2bf(v);
            if (out1 != nullptr && node >= NUM_P)   out1[(size_t)node * D_DIM + j] = v;
        }
    }
}

// ---------------------------------------------------------------------------
// Fused MFMA SAGE (round-9 proven; fallback when ws can't hold A staging)
// ---------------------------------------------------------------------------
template<int K>
__global__ __launch_bounds__(256)
void sage_mfma8(const short* __restrict__ src,
                const int*   __restrict__ idx,
                const short* __restrict__ WTg,
                float* __restrict__ out0,
                short* __restrict__ outb,
                int nb_limit,
                float* __restrict__ out1)
{
    __shared__ __align__(16) char uni[NT * 132 * 4];
    __shared__ float rnorm[NT];
    __shared__ int   sidx[NT * K];
    short* xs = reinterpret_cast<short*>(uni);
    float* ys = reinterpret_cast<float*>(uni);

    const int tid  = threadIdx.x;
    const int base = blockIdx.x * NT;

    for (int i = tid; i < NT * K; i += 256)
        sidx[i] = idx[(size_t)base * K + i];
    __syncthreads();

    {
        const int gp = tid >> 5;
        const int l  = tid & 31;
        for (int n = gp; n < NT; n += 8) {
            const int node = base + n;
            const short4 s4 = reinterpret_cast<const short4*>(src + (size_t)node * D_DIM)[l];
            float4 a4 = f4zero();
            for (int k = 0; k < K; ++k) {
                const int r = sidx[n * K + k];
                const short4 v4 = reinterpret_cast<const short4*>(src + (size_t)r * D_DIM)[l];
                a4.x += bf2f(v4.x); a4.y += bf2f(v4.y);
                a4.z += bf2f(v4.z); a4.w += bf2f(v4.w);
            }
            scale4(a4, 1.0f / (float)K);
            const int swzn = (n & 7) << 3;
            *reinterpret_cast<short4*>(&xs[n * 256 + ((l * 4) ^ swzn)])         = s4;
            *reinterpret_cast<short4*>(&xs[n * 256 + ((D_DIM + l * 4) ^ swzn)]) = pack4(a4);
        }
    }
    __syncthreads();

    const int w    = tid >> 6;
    const int l    = tid & 63;
    const int arow = l & 15;
    const int kg   = l >> 4;
    const int swz  = (arow & 7) << 3;

    f32x4 acc0 = {0.f, 0.f, 0.f, 0.f};
    f32x4 acc1 = {0.f, 0.f, 0.f, 0.f};
    const int colbase = w * 32;
    const short* b0 = WTg + (size_t)(colbase + arow) * 256 + kg * 8;
    const short* b1 = b0 + 16 * 256;

    #pragma unroll
    for (int step = 0; step < 8; ++step) {
        const int aoff = arow * 256 + ((step * 32 + kg * 8) ^ swz);
        const bf16x8 av  = *reinterpret_cast<const bf16x8*>(&xs[aoff]);
        const bf16x8 bv0 = *reinterpret_cast<const bf16x8*>(b0 + step * 32);
        const bf16x8 bv1 = *reinterpret_cast<const bf16x8*>(b1 + step * 32);
        acc0 = __builtin_amdgcn_mfma_f32_16x16x32_bf16(av, bv0, acc0, 0, 0, 0);
        acc1 = __builtin_amdgcn_mfma_f32_16x16x32_bf16(av, bv1, acc1, 0, 0, 0);
    }
    __syncthreads();

    {
        const int r0 = kg * 4;
        #pragma unroll
        for (int r = 0; r < 4; ++r) {
            float v0 = acc0[r]; v0 = v0 > 0.f ? v0 : ALPHA_ * v0;
            float v1 = acc1[r]; v1 = v1 > 0.f ? v1 : ALPHA_ * v1;
            ys[(r0 + r) * 132 + colbase + arow]      = v0;
            ys[(r0 + r) * 132 + colbase + 16 + arow] = v1;
        }
    }
    __syncthreads();

    {
        const int n  = tid >> 4;
        const int ll = tid & 15;
        float s = 0.f;
        #pragma unroll
        for (int jj = 0; jj < D_DIM; jj += 16) { const float t = ys[n * 132 + ll + jj]; s += t * t; }
        #pragma unroll
        for (int o = 8; o > 0; o >>= 1) s += __shfl_xor(s, o);
        if (ll == 0) rnorm[n] = 1.0f / fmaxf(sqrtf(s), EPS_);
    }
    __syncthreads();

    {
        const int j = tid & 127;
        const int g = tid >> 7;
        #pragma unroll
        for (int r = 0; r < 8; ++r) {
            const int n    = g * 8 + r;
            const int node = base + n;
            const float v  = ys[n * 132 + j] * rnorm[n];
            out0[(size_t)node * D_DIM + j] = v;
            if (outb != nullptr && node < nb_limit) outb[(size_t)node * D_DIM + j] = f2bf(v);
            if (out1 != nullptr && node >= NUM_P)   out1[(size_t)node * D_DIM + j] = v;
        }
    }
}

// ---------------------------------------------------------------------------
// MFMA temporal (round-9 proven). headb/outb may alias (per-row RAW in-block).
// ---------------------------------------------------------------------------
__global__ __launch_bounds__(256)
void temporal_mfma(const short* headb,
                   const float* __restrict__ hist,
                   const short* __restrict__ WhisTg,
                   const short* __restrict__ WTTg,
                   float* __restrict__ outp,
                   short* outb)
{
    __shared__ __align__(16) char uni[NT * 132 * 4];
    __shared__ float rnorm[NT];
    short* xs = reinterpret_cast<short*>(uni);
    float* ys = reinterpret_cast<float*>(uni);

    const int tid  = threadIdx.x;
    const int base = blockIdx.x * NT;
    const size_t HS = (size_t)NUM_P * D_DIM;

    {
        const int gp = tid >> 5;
        const int l  = tid & 31;
        for (int n = gp; n < NT; n += 8) {
            const size_t off = (size_t)(base + n) * D_DIM;
            const short4 h4 = reinterpret_cast<const short4*>(headb + off)[l];
            const float4 p0 = reinterpret_cast<const float4*>(hist + off)[l];
            const float4 p1 = reinterpret_cast<const float4*>(hist + off + HS)[l];
            const float4 p2 = reinterpret_cast<const float4*>(hist + off + 2 * HS)[l];
            float4 m4;
            m4.x = (p0.x + p1.x + p2.x) * (1.0f / 3.0f);
            m4.y = (p0.y + p1.y + p2.y) * (1.0f / 3.0f);
            m4.z = (p0.z + p1.z + p2.z) * (1.0f / 3.0f);
            m4.w = (p0.w + p1.w + p2.w) * (1.0f / 3.0f);
            const int swzn = (n & 7) << 3;
            *reinterpret_cast<short4*>(&xs[n * 256 + ((l * 4) ^ swzn)])         = h4;
            *reinterpret_cast<short4*>(&xs[n * 256 + ((D_DIM + l * 4) ^ swzn)]) = pack4(m4);
        }
    }
    __syncthreads();

    const int w    = tid >> 6;
    const int l    = tid & 63;
    const int arow = l & 15;
    const int kg   = l >> 4;
    const int swz  = (arow & 7) << 3;
    const int colbase = w * 32;

    {
        f32x4 t0 = {0.f, 0.f, 0.f, 0.f};
        f32x4 t1 = {0.f, 0.f, 0.f, 0.f};
        const short* b0 = WhisTg + (size_t)(colbase + arow) * 128 + kg * 8;
        const short* b1 = b0 + 16 * 128;
        #pragma unroll
        for (int step = 0; step < 4; ++step) {
            const int aoff = arow * 256 + ((D_DIM + step * 32 + kg * 8) ^ swz);
            const bf16x8 av  = *reinterpret_cast<const bf16x8*>(&xs[aoff]);
            const bf16x8 bv0 = *reinterpret_cast<const bf16x8*>(b0 + step * 32);
            const bf16x8 bv1 = *reinterpret_cast<const bf16x8*>(b1 + step * 32);
            t0 = __builtin_amdgcn_mfma_f32_16x16x32_bf16(av, bv0, t0, 0, 0, 0);
            t1 = __builtin_amdgcn_mfma_f32_16x16x32_bf16(av, bv1, t1, 0, 0, 0);
        }
        __syncthreads();

        #pragma unroll
        for (int r = 0; r < 4; ++r) {
            const int node = kg * 4 + r;
            const int swzn = (node & 7) << 3;
            xs[node * 256 + ((D_DIM + colbase + arow) ^ swzn)]      = f2bf(t0[r]);
            xs[node * 256 + ((D_DIM + colbase + 16 + arow) ^ swzn)] = f2bf(t1[r]);
        }
    }
    __syncthreads();

    f32x4 acc0 = {0.f, 0.f, 0.f, 0.f};
    f32x4 acc1 = {0.f, 0.f, 0.f, 0.f};
    {
        const short* b0 = WTTg + (size_t)(colbase + arow) * 256 + kg * 8;
        const short* b1 = b0 + 16 * 256;
        #pragma unroll
        for (int step = 0; step < 8; ++step) {
            const int aoff = arow * 256 + ((step * 32 + kg * 8) ^ swz);
            const bf16x8 av  = *reinterpret_cast<const bf16x8*>(&xs[aoff]);
            const bf16x8 bv0 = *reinterpret_cast<const bf16x8*>(b0 + step * 32);
            const bf16x8 bv1 = *reinterpret_cast<const bf16x8*>(b1 + step * 32);
            acc0 = __builtin_amdgcn_mfma_f32_16x16x32_bf16(av, bv0, acc0, 0, 0, 0);
            acc1 = __builtin_amdgcn_mfma_f32_16x16x32_bf16(av, bv1, acc1, 0, 0, 0);
        }
    }
    __syncthreads();

    {
        const int r0 = kg * 4;
        #pragma unroll
        for (int r = 0; r < 4; ++r) {
            float v0 = acc0[r]; v0 = v0 > 0.f ? v0 : ALPHA_ * v0;
            float v1 = acc1[r]; v1 = v1 > 0.f ? v1 : ALPHA_ * v1;
            ys[(r0 + r) * 132 + colbase + arow]      = v0;
            ys[(r0 + r) * 132 + colbase + 16 + arow] = v1;
        }
    }
    __syncthreads();

    {
        const int n  = tid >> 4;
        const int ll = tid & 15;
        float s = 0.f;
        #pragma unroll
        for (int jj = 0; jj < D_DIM; jj += 16) { const float t = ys[n * 132 + ll + jj]; s += t * t; }
        #pragma unroll
        for (int o = 8; o > 0; o >>= 1) s += __shfl_xor(s, o);
        if (ll == 0) rnorm[n] = 1.0f / fmaxf(sqrtf(s), EPS_);
    }
    __syncthreads();

    {
        const int j = tid & 127;
        const int g = tid >> 7;
        #pragma unroll
        for (int r = 0; r < 8; ++r) {
            const int n = g * 8 + r;
            const float v = ys[n * 132 + j] * rnorm[n];
            const size_t o = (size_t)(base + n) * D_DIM + j;
            if (outp != nullptr) outp[o] = v;
            if (outb != nullptr) outb[o] = f2bf(v);
        }
    }
}

// ---------------------------------------------------------------------------
// fp32 temporal (fallback)
// ---------------------------------------------------------------------------
__global__ __launch_bounds__(256)
void temporal_v8(const float* __restrict__ head,
                 const float* __restrict__ hist,
                 const float* __restrict__ Whis,
                 const float* __restrict__ WTm,
                 float* __restrict__ outp,
                 short* __restrict__ outb)
{
    __shared__ float xs[NT][2 * D_DIM];
    __shared__ float hm[NT][D_DIM];
    __shared__ float rnorm[NT];

    const int tid  = threadIdx.x;
    const int base = blockIdx.x * NT;
    const size_t HS = (size_t)NUM_P * D_DIM;

    {
        const int gp = tid >> 5;
        const int l  = tid & 31;
        for (int n = gp; n < NT; n += 8) {
            const size_t off = (size_t)(base + n) * D_DIM;
            const float4 h4 = reinterpret_cast<const float4*>(head + off)[l];
            const float4 p0 = reinterpret_cast<const float4*>(hist + off)[l];
            const float4 p1 = reinterpret_cast<const float4*>(hist + off + HS)[l];
            const float4 p2 = reinterpret_cast<const float4*>(hist + off + 2 * HS)[l];
            float4 m4;
            m4.x = (p0.x + p1.x + p2.x) * (1.0f / 3.0f);
            m4.y = (p0.y + p1.y + p2.y) * (1.0f / 3.0f);
            m4.z = (p0.z + p1.z + p2.z) * (1.0f / 3.0f);
            m4.w = (p0.w + p1.w + p2.w) * (1.0f / 3.0f);
            reinterpret_cast<float4*>(&xs[n][0])[l] = h4;
            reinterpret_cast<float4*>(&hm[n][0])[l] = m4;
        }
    }
    __syncthreads();

    const int j  = tid & 127;
    const int g  = tid >> 7;
    const int nb = g * 8;

    {
        float a2[8];
        #pragma unroll
        for (int r = 0; r < 8; ++r) a2[r] = 0.f;
        for (int c4 = 0; c4 < D_DIM / 4; ++c4) {
            const int c = c4 * 4;
            const float w0 = Whis[(size_t)(c + 0) * D_DIM + j];
            const float w1 = Whis[(size_t)(c + 1) * D_DIM + j];
            const float w2 = Whis[(size_t)(c + 2) * D_DIM + j];
            const float w3 = Whis[(size_t)(c + 3) * D_DIM + j];
            #pragma unroll
            for (int r = 0; r < 8; ++r) {
                const float4 xv = *reinterpret_cast<const float4*>(&hm[nb + r][c]);
                a2[r] = fmaf(xv.w, w3, fmaf(xv.z, w2, fmaf(xv.y, w1, fmaf(xv.x, w0, a2[r]))));
            }
        }
        __syncthreads();
        #pragma unroll
        for (int r = 0; r < 8; ++r) xs[nb + r][D_DIM + j] = a2[r];
    }
    __syncthreads();

    float acc[8];
    #pragma unroll
    for (int r = 0; r < 8; ++r) acc[r] = 0.f;
    for (int c4 = 0; c4 < (2 * D_DIM) / 4; ++c4) {
        const int c = c4 * 4;
        const float w0 = WTm[(size_t)(c + 0) * D_DIM + j];
        const float w1 = WTm[(size_t)(c + 1) * D_DIM + j];
        const float w2 = WTm[(size_t)(c + 2) * D_DIM + j];
        const float w3 = WTm[(size_t)(c + 3) * D_DIM + j];
        #pragma unroll
        for (int r = 0; r < 8; ++r) {
            const float4 xv = *reinterpret_cast<const float4*>(&xs[nb + r][c]);
            acc[r] = fmaf(xv.w, w3, fmaf(xv.z, w2, fmaf(xv.y, w1, fmaf(xv.x, w0, acc[r]))));
        }
    }
    __syncthreads();

    #pragma unroll
    for (int r = 0; r < 8; ++r) {
        float v = acc[r];
        v = v > 0.f ? v : ALPHA_ * v;
        xs[nb + r][j] = v;
    }
    __syncthreads();

    {
        const int n  = tid >> 4;
        const int ll = tid & 15;
        float s = 0.f;
        #pragma unroll
        for (int jj = ll; jj < D_DIM; jj += 16) { const float t = xs[n][jj]; s += t * t; }
        #pragma unroll
        for (int o = 8; o > 0; o >>= 1) s += __shfl_xor(s, o);
        if (ll == 0) rnorm[n] = 1.0f / fmaxf(sqrtf(s), EPS_);
    }
    __syncthreads();

    #pragma unroll
    for (int r = 0; r < 8; ++r) {
        const int n = nb + r;
        const float v = xs[n][j] * rnorm[n];
        const size_t o = (size_t)(base + n) * D_DIM + j;
        if (outp != nullptr) outp[o] = v;
        if (outb != nullptr) outb[o] = f2bf(v);
    }
}

// ---------------------------------------------------------------------------
// fp32 SAGE (last-resort fallback)
// ---------------------------------------------------------------------------
template<int K, bool SPLIT>
__global__ __launch_bounds__(256)
void sage_v5(const float* __restrict__ srcLow,
             const float* __restrict__ srcHigh,
             const int*   __restrict__ idx,
             const float* __restrict__ W,
             float* __restrict__ out0,
             float* __restrict__ out1)
{
    __shared__ float xs[NT][2 * D_DIM];
    __shared__ int   sidx[NT * K];
    __shared__ float rnorm[NT];

    const int tid  = threadIdx.x;
    const int base = blockIdx.x * NT;

    for (int i = tid; i < NT * K; i += 256)
        sidx[i] = idx[(size_t)base * K + i];
    __syncthreads();

    {
        const int gp = tid >> 5;
        const int l  = tid & 31;
        for (int n = gp; n < NT; n += 8) {
            const int node = base + n;
            const float* sp = (!SPLIT || node < NUM_P) ? srcLow : srcHigh;
            const float4 s4 = reinterpret_cast<const float4*>(sp + (size_t)node * D_DIM)[l];
            float4 a4 = f4zero();
            for (int k = 0; k < K; ++k) {
                const int r = sidx[n * K + k];
                const float* rp = (!SPLIT || r < NUM_P) ? srcLow : srcHigh;
                const float4 v4 = reinterpret_cast<const float4*>(rp + (size_t)r * D_DIM)[l];
                a4.x += v4.x; a4.y += v4.y; a4.z += v4.z; a4.w += v4.w;
            }
            scale4(a4, 1.0f / (float)K);
            reinterpret_cast<float4*>(&xs[n][0])[l]     = s4;
            reinterpret_cast<float4*>(&xs[n][D_DIM])[l] = a4;
        }
    }
    __syncthreads();

    const int j  = tid & 127;
    const int g  = tid >> 7;
    const int nb = g * 8;

    float acc[8];
    #pragma unroll
    for (int r = 0; r < 8; ++r) acc[r] = 0.f;
    for (int c4 = 0; c4 < (2 * D_DIM) / 4; ++c4) {
        const int c = c4 * 4;
        const float w0 = W[(size_t)(c + 0) * D_DIM + j];
        const float w1 = W[(size_t)(c + 1) * D_DIM + j];
        const float w2 = W[(size_t)(c + 2) * D_DIM + j];
        const float w3 = W[(size_t)(c + 3) * D_DIM + j];
        #pragma unroll
        for (int r = 0; r < 8; ++r) {
            const float4 xv = *reinterpret_cast<const float4*>(&xs[nb + r][c]);
            acc[r] = fmaf(xv.w, w3, fmaf(xv.z, w2, fmaf(xv.y, w1, fmaf(xv.x, w0, acc[r]))));
        }
    }
    __syncthreads();

    #pragma unroll
    for (int r = 0; r < 8; ++r) {
        float v = acc[r];
        v = v > 0.f ? v : ALPHA_ * v;
        xs[nb + r][j] = v;
    }
    __syncthreads();

    {
        const int n  = tid >> 4;
        const int ll = tid & 15;
        float s = 0.f;
        #pragma unroll
        for (int jj = ll; jj < D_DIM; jj += 16) { const float t = xs[n][jj]; s += t * t; }
        #pragma unroll
        for (int o = 8; o > 0; o >>= 1) s += __shfl_xor(s, o);
        if (ll == 0) rnorm[n] = 1.0f / fmaxf(sqrtf(s), EPS_);
    }
    __syncthreads();

    #pragma unroll
    for (int r = 0; r < 8; ++r) {
        const int n    = nb + r;
        const int node = base + n;
        const float v  = xs[n][j] * rnorm[n];
        out0[(size_t)node * D_DIM + j] = v;
        if (out1 != nullptr && node >= NUM_P) out1[(size_t)node * D_DIM + j] = v;
    }
}

// ---------------------------------------------------------------------------
extern "C" void kernel_launch(void* const* d_in, const int* in_sizes, int n_in,
                              void* d_out, int out_size, void* d_ws, size_t ws_size,
                              hipStream_t stream)
{
    (void)in_sizes; (void)n_in; (void)out_size;

    const float* feats = (const float*)d_in[0];
    const int*   idx1  = (const int*)  d_in[1];
    const int*   idx2  = (const int*)  d_in[2];
    const float* hist1 = (const float*)d_in[3];
    const float* hist2 = (const float*)d_in[4];
    const float* W1    = (const float*)d_in[5];
    const float* W2    = (const float*)d_in[6];
    const float* Whis  = (const float*)d_in[7];
    const float* WTm   = (const float*)d_in[8];

    float* out = (float*)d_out;
    float* h1o = out;
    float* h2o = out + (size_t)N_NODES * D_DIM;
    float* fo  = out + 2 * (size_t)N_NODES * D_DIM;

    const int sage_blocks   = N_NODES / NT;          // 3125
    const int temp_blocks   = NUM_P   / NT;          // 1250
    const int gather_blocks = N_NODES * 32 / 256;    // 6250

    const size_t SZ_N  = (size_t)N_NODES * D_DIM;    // 6.4M elems
    const size_t SZ_P  = (size_t)NUM_P  * D_DIM;     // 2.56M elems
    const size_t SZ_A  = (size_t)N_NODES * 2 * D_DIM; // 12.8M shorts (A staging)
    const size_t WOFF  = 114688;
    const size_t needNew = (WOFF + 2 * SZ_N + SZ_P + SZ_A) * 2;  // ~56.5 MB
    const size_t needA   = (WOFF + 2 * SZ_N + SZ_P) * 2;         // ~30.9 MB
    const size_t needB   = (WOFF + 2 * SZ_N) * 2;                // ~25.8 MB

    short* wsp  = (short*)d_ws;
    short* W1T  = wsp;
    short* W2T  = wsp + 32768;
    short* WhT  = wsp + 65536;
    short* WTT  = wsp + 81920;
    short* fb   = wsp + WOFF;          // bf16 feats  [N,128]
    short* hb   = fb + SZ_N;           // bf16 h1/f1  [N,128]
    short* h2b  = hb + SZ_N;           // bf16 h2     [NUM_P,128]
    short* Ast  = h2b + SZ_P;          // staged A tiles [N/16][16][256]

    if (ws_size >= needNew) {
        wcvt2_kernel<<<448, 256, 0, stream>>>(W1, W2, Whis, WTm, wsp);
        fcvt_kernel<<<(int)(SZ_N / 1024), 256, 0, stream>>>(feats, fb);

        // sage1: barrier-free gather -> staged A -> slim GEMM
        gather_a<25><<<gather_blocks, 256, 0, stream>>>(fb, idx1, Ast);
        sage_gemm<<<sage_blocks, 256, 0, stream>>>(Ast, W1T, h1o, hb, N_NODES, nullptr);
        // f1 -> bf16 into hb rows [0,NUM)
        temporal_mfma<<<temp_blocks, 256, 0, stream>>>(hb, hist1, WhT, WTT, nullptr, hb);
        // sage2
        gather_a<10><<<gather_blocks, 256, 0, stream>>>(hb, idx2, Ast);
        sage_gemm<<<sage_blocks, 256, 0, stream>>>(Ast, W2T, h2o, h2b, NUM_P, fo);
        // f2 -> fo rows [0,NUM)
        temporal_mfma<<<temp_blocks, 256, 0, stream>>>(h2b, hist2, WhT, WTT, fo, nullptr);
    } else if (ws_size >= needA) {
        wcvt2_kernel<<<448, 256, 0, stream>>>(W1, W2, Whis, WTm, wsp);
        fcvt_kernel<<<(int)(SZ_N / 1024), 256, 0, stream>>>(feats, fb);

        sage_mfma8<25><<<sage_blocks, 256, 0, stream>>>(fb, idx1, W1T, h1o, hb, N_NODES, nullptr);
        temporal_mfma<<<temp_blocks, 256, 0, stream>>>(hb, hist1, WhT, WTT, nullptr, hb);
        sage_mfma8<10><<<sage_blocks, 256, 0, stream>>>(hb, idx2, W2T, h2o, h2b, NUM_P, fo);
        temporal_mfma<<<temp_blocks, 256, 0, stream>>>(h2b, hist2, WhT, WTT, fo, nullptr);
    } else if (ws_size >= needB) {
        wcvt2_kernel<<<448, 256, 0, stream>>>(W1, W2, Whis, WTm, wsp);
        fcvt_kernel<<<(int)(SZ_N / 1024), 256, 0, stream>>>(feats, fb);

        sage_mfma8<25><<<sage_blocks, 256, 0, stream>>>(fb, idx1, W1T, h1o, hb, N_NODES, nullptr);
        temporal_v8<<<temp_blocks, 256, 0, stream>>>(h1o, hist1, Whis, WTm, nullptr, hb);
        sage_mfma8<10><<<sage_blocks, 256, 0, stream>>>(hb, idx2, W2T, h2o, nullptr, 0, fo);
        temporal_v8<<<temp_blocks, 256, 0, stream>>>(h2o, hist2, Whis, WTm, fo, nullptr);
    } else {
        sage_v5<25, false><<<sage_blocks, 256, 0, stream>>>(feats, feats, idx1, W1, h1o, nullptr);
        temporal_v8<<<temp_blocks, 256, 0, stream>>>(h1o, hist1, Whis, WTm, fo, nullptr);
        sage_v5<10, true><<<sage_blocks, 256, 0, stream>>>(fo, h1o, idx2, W2, h2o, fo);
        temporal_v8<<<temp_blocks, 256, 0, stream>>>(h2o, hist2, Whis, WTm, fo, nullptr);
    }
}

// Round 15
// 140.536 us; speedup vs baseline: 1.2904x; 1.2904x over previous
//
#include <hip/hip_runtime.h>
#include <hip/hip_bf16.h>

#define N_NODES 50000
#define NUM_P   20000
#define D_DIM   128
#define ALPHA_  0.2f
#define EPS_    1e-12f
#define NT      16      // nodes per tile (50000 = 3125*16, 20000 = 1250*16)

typedef __attribute__((ext_vector_type(8))) short bf16x8;
typedef __attribute__((ext_vector_type(4))) float f32x4;
typedef __attribute__((ext_vector_type(2))) float f32x2;

#if defined(__has_builtin)
#if __has_builtin(__builtin_amdgcn_cvt_pk_f32_fp8) && __has_builtin(__builtin_amdgcn_cvt_pk_fp8_f32)
#define HAVE_HW_FP8 1
#endif
#endif

__device__ __forceinline__ float4 f4zero() { return make_float4(0.f, 0.f, 0.f, 0.f); }

__device__ __forceinline__ void scale4(float4& v, const float s) {
    v.x *= s; v.y *= s; v.z *= s; v.w *= s;
}

__device__ __forceinline__ short f2bf(float f) {
    __hip_bfloat16 h = __float2bfloat16(f);
    return *reinterpret_cast<short*>(&h);
}

__device__ __forceinline__ float bf2f(short u) {
    union { unsigned i; float f; } c;
    c.i = ((unsigned)(unsigned short)u) << 16;
    return c.f;
}

__device__ __forceinline__ short4 pack4(const float4 v) {
    short4 s;
    s.x = f2bf(v.x); s.y = f2bf(v.y); s.z = f2bf(v.z); s.w = f2bf(v.w);
    return s;
}

// ---------------- fp8 e4m3 helpers (HW cvt on gfx950, SW fallback) ----------
__device__ __forceinline__ float fp8_sw_dec(unsigned b) {
    unsigned e = (b >> 3) & 0xF, m = b & 7;
    float v = (e == 0) ? (float)m * 0.001953125f
                       : __uint_as_float(((e + 120u) << 23) | (m << 20));
    return (b & 0x80) ? -v : v;
}

__device__ __forceinline__ unsigned fp8_sw_enc(float f) {
    unsigned s = f < 0.f ? 0x80u : 0u;
    float af = fabsf(f);
    if (af >= 448.f) return s | 0x7E;
    if (af < 0.0009765625f) return s;
    int e; float m = frexpf(af, &e);
    int E = e - 1;
    if (E < -6) {
        int q = (int)rintf(af * 512.f);
        if (q >= 8) return s | 0x08;
        return s | (unsigned)q;
    }
    int q = (int)rintf(m * 16.f);
    if (q == 16) { q = 8; ++E; }
    if (E > 8) return s | 0x7E;
    return s | ((unsigned)(E + 7) << 3) | (unsigned)(q - 8);
}

template<bool HI>
__device__ __forceinline__ f32x2 fp8x2_dec(unsigned v) {
#ifdef HAVE_HW_FP8
    return __builtin_amdgcn_cvt_pk_f32_fp8((int)v, HI);
#else
    f32x2 r;
    unsigned b0 = HI ? ((v >> 16) & 0xFF) : (v & 0xFF);
    unsigned b1 = HI ? (v >> 24)          : ((v >> 8) & 0xFF);
    r[0] = fp8_sw_dec(b0); r[1] = fp8_sw_dec(b1);
    return r;
#endif
}

__device__ __forceinline__ unsigned char f2fp8(float v) {
#ifdef HAVE_HW_FP8
    return (unsigned char)(__builtin_amdgcn_cvt_pk_fp8_f32(v, v, 0, false) & 0xFF);
#else
    return (unsigned char)fp8_sw_enc(v);
#endif
}

__device__ __forceinline__ unsigned pack4_fp8(const float4 v) {
#ifdef HAVE_HW_FP8
    int lo = __builtin_amdgcn_cvt_pk_fp8_f32(v.x, v.y, 0, false);
    return (unsigned)__builtin_amdgcn_cvt_pk_fp8_f32(v.z, v.w, lo, true);
#else
    return fp8_sw_enc(v.x) | (fp8_sw_enc(v.y) << 8) |
           (fp8_sw_enc(v.z) << 16) | (fp8_sw_enc(v.w) << 24);
#endif
}

// ---------------------------------------------------------------------------
// Weight pre-transpose+cvt to bf16 (W1T | W2T | WhisT | WTT)
// ---------------------------------------------------------------------------
__global__ __launch_bounds__(256)
void wcvt2_kernel(const float* __restrict__ W1, const float* __restrict__ W2,
                  const float* __restrict__ Whis, const float* __restrict__ WTm,
                  short* __restrict__ o)
{
    const int i = blockIdx.x * 256 + threadIdx.x;   // 0..114687
    float v;
    if (i < 65536) {
        const float* W = (i < 32768) ? W1 : W2;
        const int t = i & 32767;
        v = W[(size_t)(t & 255) * D_DIM + (t >> 8)];
    } else if (i < 81920) {
        const int t = i - 65536;
        v = Whis[(size_t)(t & 127) * D_DIM + (t >> 7)];
    } else {
        const int t = i - 81920;
        v = WTm[(size_t)(t & 255) * D_DIM + (t >> 8)];
    }
    o[i] = f2bf(v);
}

// fp32 -> bf16 mirror + fp8 mirror (element count multiple of 1024)
__global__ __launch_bounds__(256)
void fcvt8_kernel(const float* __restrict__ in, short* __restrict__ ob,
                  unsigned* __restrict__ o8)
{
    const int i = blockIdx.x * 256 + threadIdx.x;
    const float4 v = reinterpret_cast<const float4*>(in)[i];
    reinterpret_cast<short4*>(ob)[i] = pack4(v);
    o8[i] = pack4_fp8(v);
}

// fp32 -> bf16 mirror only
__global__ __launch_bounds__(256)
void fcvt_kernel(const float* __restrict__ in, short* __restrict__ ob)
{
    const int i = blockIdx.x * 256 + threadIdx.x;
    const float4 v = reinterpret_cast<const float4*>(in)[i];
    reinterpret_cast<short4*>(ob)[i] = pack4(v);
}

// ---------------------------------------------------------------------------
// Fused MFMA SAGE, fp8 neighbor gather:
//   srcB bf16 [*,128] (self rows), src8 fp8 [*,128] (neighbor rows).
// ---------------------------------------------------------------------------
template<int K>
__global__ __launch_bounds__(256)
void sage_f8(const short*    __restrict__ srcB,
             const unsigned* __restrict__ src8,
             const int*      __restrict__ idx,
             const short*    __restrict__ WTg,     // [128][256] bf16 = W transposed
             float* __restrict__ out0,
             short* __restrict__ outb, int nb_limit,
             unsigned char* __restrict__ out8, int n8_limit,
             float* __restrict__ out1)
{
    __shared__ __align__(16) char uni[NT * 132 * 4];
    __shared__ float rnorm[NT];
    __shared__ int   sidx[NT * K];
    short* xs = reinterpret_cast<short*>(uni);   // [n][256] bf16, swizzled
    float* ys = reinterpret_cast<float*>(uni);   // [n][132] fp32

    const int tid  = threadIdx.x;
    const int base = blockIdx.x * NT;

    for (int i = tid; i < NT * K; i += 256)
        sidx[i] = idx[(size_t)base * K + i];
    __syncthreads();

    // ---- gather: self bf16 (8B/lane), neighbors fp8 (4B/lane) ----
    {
        const int gp = tid >> 5;
        const int l  = tid & 31;
        for (int n = gp; n < NT; n += 8) {
            const int node = base + n;
            const short4 s4 = reinterpret_cast<const short4*>(srcB + (size_t)node * D_DIM)[l];
            float4 a4 = f4zero();
            for (int k = 0; k < K; ++k) {
                const int r = sidx[n * K + k];
                const unsigned v = src8[(size_t)r * 32 + l];
                const f32x2 lo = fp8x2_dec<false>(v);
                const f32x2 hi = fp8x2_dec<true>(v);
                a4.x += lo[0]; a4.y += lo[1]; a4.z += hi[0]; a4.w += hi[1];
            }
            scale4(a4, 1.0f / (float)K);
            const int swzn = (n & 7) << 3;
            *reinterpret_cast<short4*>(&xs[n * 256 + ((l * 4) ^ swzn)])         = s4;
            *reinterpret_cast<short4*>(&xs[n * 256 + ((D_DIM + l * 4) ^ swzn)]) = pack4(a4);
        }
    }
    __syncthreads();

    // ---- MFMA: wave w -> cols [32w, 32w+32), K=256 in 8 steps ----
    const int w    = tid >> 6;
    const int l    = tid & 63;
    const int arow = l & 15;
    const int kg   = l >> 4;
    const int swz  = (arow & 7) << 3;

    f32x4 acc0 = {0.f, 0.f, 0.f, 0.f};
    f32x4 acc1 = {0.f, 0.f, 0.f, 0.f};
    const int colbase = w * 32;
    const short* b0 = WTg + (size_t)(colbase + arow) * 256 + kg * 8;
    const short* b1 = b0 + 16 * 256;

    #pragma unroll
    for (int step = 0; step < 8; ++step) {
        const int aoff = arow * 256 + ((step * 32 + kg * 8) ^ swz);
        const bf16x8 av  = *reinterpret_cast<const bf16x8*>(&xs[aoff]);
        const bf16x8 bv0 = *reinterpret_cast<const bf16x8*>(b0 + step * 32);
        const bf16x8 bv1 = *reinterpret_cast<const bf16x8*>(b1 + step * 32);
        acc0 = __builtin_amdgcn_mfma_f32_16x16x32_bf16(av, bv0, acc0, 0, 0, 0);
        acc1 = __builtin_amdgcn_mfma_f32_16x16x32_bf16(av, bv1, acc1, 0, 0, 0);
    }
    __syncthreads();

    // ---- epilogue: leaky -> ys (D layout: node=(l>>4)*4+r, col-local=l&15)
    {
        const int r0 = kg * 4;
        #pragma unroll
        for (int r = 0; r < 4; ++r) {
            float v0 = acc0[r]; v0 = v0 > 0.f ? v0 : ALPHA_ * v0;
            float v1 = acc1[r]; v1 = v1 > 0.f ? v1 : ALPHA_ * v1;
            ys[(r0 + r) * 132 + colbase + arow]      = v0;
            ys[(r0 + r) * 132 + colbase + 16 + arow] = v1;
        }
    }
    __syncthreads();

    {
        const int n  = tid >> 4;
        const int ll = tid & 15;
        float s = 0.f;
        #pragma unroll
        for (int jj = 0; jj < D_DIM; jj += 16) { const float t = ys[n * 132 + ll + jj]; s += t * t; }
        #pragma unroll
        for (int o = 8; o > 0; o >>= 1) s += __shfl_xor(s, o);
        if (ll == 0) rnorm[n] = 1.0f / fmaxf(sqrtf(s), EPS_);
    }
    __syncthreads();

    {
        const int j = tid & 127;
        const int g = tid >> 7;
        #pragma unroll
        for (int r = 0; r < 8; ++r) {
            const int n    = g * 8 + r;
            const int node = base + n;
            const float v  = ys[n * 132 + j] * rnorm[n];
            out0[(size_t)node * D_DIM + j] = v;
            if (outb != nullptr && node < nb_limit) outb[(size_t)node * D_DIM + j] = f2bf(v);
            if (out8 != nullptr && node < n8_limit) out8[(size_t)node * D_DIM + j] = f2fp8(v);
            if (out1 != nullptr && node >= NUM_P)   out1[(size_t)node * D_DIM + j] = v;
        }
    }
}

// ---------------------------------------------------------------------------
// Fused MFMA SAGE, bf16 gather (round-10 proven; fallback)
// ---------------------------------------------------------------------------
template<int K>
__global__ __launch_bounds__(256)
void sage_mfma8(const short* __restrict__ src,
                const int*   __restrict__ idx,
                const short* __restrict__ WTg,
                float* __restrict__ out0,
                short* __restrict__ outb,
                int nb_limit,
                float* __restrict__ out1)
{
    __shared__ __align__(16) char uni[NT * 132 * 4];
    __shared__ float rnorm[NT];
    __shared__ int   sidx[NT * K];
    short* xs = reinterpret_cast<short*>(uni);
    float* ys = reinterpret_cast<float*>(uni);

    const int tid  = threadIdx.x;
    const int base = blockIdx.x * NT;

    for (int i = tid; i < NT * K; i += 256)
        sidx[i] = idx[(size_t)base * K + i];
    __syncthreads();

    {
        const int gp = tid >> 5;
        const int l  = tid & 31;
        for (int n = gp; n < NT; n += 8) {
            const int node = base + n;
            const short4 s4 = reinterpret_cast<const short4*>(src + (size_t)node * D_DIM)[l];
            float4 a4 = f4zero();
            for (int k = 0; k < K; ++k) {
                const int r = sidx[n * K + k];
                const short4 v4 = reinterpret_cast<const short4*>(src + (size_t)r * D_DIM)[l];
                a4.x += bf2f(v4.x); a4.y += bf2f(v4.y);
                a4.z += bf2f(v4.z); a4.w += bf2f(v4.w);
            }
            scale4(a4, 1.0f / (float)K);
            const int swzn = (n & 7) << 3;
            *reinterpret_cast<short4*>(&xs[n * 256 + ((l * 4) ^ swzn)])         = s4;
            *reinterpret_cast<short4*>(&xs[n * 256 + ((D_DIM + l * 4) ^ swzn)]) = pack4(a4);
        }
    }
    __syncthreads();

    const int w    = tid >> 6;
    const int l    = tid & 63;
    const int arow = l & 15;
    const int kg   = l >> 4;
    const int swz  = (arow & 7) << 3;

    f32x4 acc0 = {0.f, 0.f, 0.f, 0.f};
    f32x4 acc1 = {0.f, 0.f, 0.f, 0.f};
    const int colbase = w * 32;
    const short* b0 = WTg + (size_t)(colbase + arow) * 256 + kg * 8;
    const short* b1 = b0 + 16 * 256;

    #pragma unroll
    for (int step = 0; step < 8; ++step) {
        const int aoff = arow * 256 + ((step * 32 + kg * 8) ^ swz);
        const bf16x8 av  = *reinterpret_cast<const bf16x8*>(&xs[aoff]);
        const bf16x8 bv0 = *reinterpret_cast<const bf16x8*>(b0 + step * 32);
        const bf16x8 bv1 = *reinterpret_cast<const bf16x8*>(b1 + step * 32);
        acc0 = __builtin_amdgcn_mfma_f32_16x16x32_bf16(av, bv0, acc0, 0, 0, 0);
        acc1 = __builtin_amdgcn_mfma_f32_16x16x32_bf16(av, bv1, acc1, 0, 0, 0);
    }
    __syncthreads();

    {
        const int r0 = kg * 4;
        #pragma unroll
        for (int r = 0; r < 4; ++r) {
            float v0 = acc0[r]; v0 = v0 > 0.f ? v0 : ALPHA_ * v0;
            float v1 = acc1[r]; v1 = v1 > 0.f ? v1 : ALPHA_ * v1;
            ys[(r0 + r) * 132 + colbase + arow]      = v0;
            ys[(r0 + r) * 132 + colbase + 16 + arow] = v1;
        }
    }
    __syncthreads();

    {
        const int n  = tid >> 4;
        const int ll = tid & 15;
        float s = 0.f;
        #pragma unroll
        for (int jj = 0; jj < D_DIM; jj += 16) { const float t = ys[n * 132 + ll + jj]; s += t * t; }
        #pragma unroll
        for (int o = 8; o > 0; o >>= 1) s += __shfl_xor(s, o);
        if (ll == 0) rnorm[n] = 1.0f / fmaxf(sqrtf(s), EPS_);
    }
    __syncthreads();

    {
        const int j = tid & 127;
        const int g = tid >> 7;
        #pragma unroll
        for (int r = 0; r < 8; ++r) {
            const int n    = g * 8 + r;
            const int node = base + n;
            const float v  = ys[n * 132 + j] * rnorm[n];
            out0[(size_t)node * D_DIM + j] = v;
            if (outb != nullptr && node < nb_limit) outb[(size_t)node * D_DIM + j] = f2bf(v);
            if (out1 != nullptr && node >= NUM_P)   out1[(size_t)node * D_DIM + j] = v;
        }
    }
}

// ---------------------------------------------------------------------------
// MFMA temporal (round-9 proven). headb/outb/out8 may alias headb's table
// (per-row read-then-write within the owning block only).
// ---------------------------------------------------------------------------
__global__ __launch_bounds__(256)
void temporal_mfma(const short* headb,
                   const float* __restrict__ hist,
                   const short* __restrict__ WhisTg,
                   const short* __restrict__ WTTg,
                   float* __restrict__ outp,
                   short* outb,
                   unsigned char* out8)
{
    __shared__ __align__(16) char uni[NT * 132 * 4];
    __shared__ float rnorm[NT];
    short* xs = reinterpret_cast<short*>(uni);
    float* ys = reinterpret_cast<float*>(uni);

    const int tid  = threadIdx.x;
    const int base = blockIdx.x * NT;
    const size_t HS = (size_t)NUM_P * D_DIM;

    {
        const int gp = tid >> 5;
        const int l  = tid & 31;
        for (int n = gp; n < NT; n += 8) {
            const size_t off = (size_t)(base + n) * D_DIM;
            const short4 h4 = reinterpret_cast<const short4*>(headb + off)[l];
            const float4 p0 = reinterpret_cast<const float4*>(hist + off)[l];
            const float4 p1 = reinterpret_cast<const float4*>(hist + off + HS)[l];
            const float4 p2 = reinterpret_cast<const float4*>(hist + off + 2 * HS)[l];
            float4 m4;
            m4.x = (p0.x + p1.x + p2.x) * (1.0f / 3.0f);
            m4.y = (p0.y + p1.y + p2.y) * (1.0f / 3.0f);
            m4.z = (p0.z + p1.z + p2.z) * (1.0f / 3.0f);
            m4.w = (p0.w + p1.w + p2.w) * (1.0f / 3.0f);
            const int swzn = (n & 7) << 3;
            *reinterpret_cast<short4*>(&xs[n * 256 + ((l * 4) ^ swzn)])         = h4;
            *reinterpret_cast<short4*>(&xs[n * 256 + ((D_DIM + l * 4) ^ swzn)]) = pack4(m4);
        }
    }
    __syncthreads();

    const int w    = tid >> 6;
    const int l    = tid & 63;
    const int arow = l & 15;
    const int kg   = l >> 4;
    const int swz  = (arow & 7) << 3;
    const int colbase = w * 32;

    {
        f32x4 t0 = {0.f, 0.f, 0.f, 0.f};
        f32x4 t1 = {0.f, 0.f, 0.f, 0.f};
        const short* b0 = WhisTg + (size_t)(colbase + arow) * 128 + kg * 8;
        const short* b1 = b0 + 16 * 128;
        #pragma unroll
        for (int step = 0; step < 4; ++step) {
            const int aoff = arow * 256 + ((D_DIM + step * 32 + kg * 8) ^ swz);
            const bf16x8 av  = *reinterpret_cast<const bf16x8*>(&xs[aoff]);
            const bf16x8 bv0 = *reinterpret_cast<const bf16x8*>(b0 + step * 32);
            const bf16x8 bv1 = *reinterpret_cast<const bf16x8*>(b1 + step * 32);
            t0 = __builtin_amdgcn_mfma_f32_16x16x32_bf16(av, bv0, t0, 0, 0, 0);
            t1 = __builtin_amdgcn_mfma_f32_16x16x32_bf16(av, bv1, t1, 0, 0, 0);
        }
        __syncthreads();

        #pragma unroll
        for (int r = 0; r < 4; ++r) {
            const int node = kg * 4 + r;
            const int swzn = (node & 7) << 3;
            xs[node * 256 + ((D_DIM + colbase + arow) ^ swzn)]      = f2bf(t0[r]);
            xs[node * 256 + ((D_DIM + colbase + 16 + arow) ^ swzn)] = f2bf(t1[r]);
        }
    }
    __syncthreads();

    f32x4 acc0 = {0.f, 0.f, 0.f, 0.f};
    f32x4 acc1 = {0.f, 0.f, 0.f, 0.f};
    {
        const short* b0 = WTTg + (size_t)(colbase + arow) * 256 + kg * 8;
        const short* b1 = b0 + 16 * 256;
        #pragma unroll
        for (int step = 0; step < 8; ++step) {
            const int aoff = arow * 256 + ((step * 32 + kg * 8) ^ swz);
            const bf16x8 av  = *reinterpret_cast<const bf16x8*>(&xs[aoff]);
            const bf16x8 bv0 = *reinterpret_cast<const bf16x8*>(b0 + step * 32);
            const bf16x8 bv1 = *reinterpret_cast<const bf16x8*>(b1 + step * 32);
            acc0 = __builtin_amdgcn_mfma_f32_16x16x32_bf16(av, bv0, acc0, 0, 0, 0);
            acc1 = __builtin_amdgcn_mfma_f32_16x16x32_bf16(av, bv1, acc1, 0, 0, 0);
        }
    }
    __syncthreads();

    {
        const int r0 = kg * 4;
        #pragma unroll
        for (int r = 0; r < 4; ++r) {
            float v0 = acc0[r]; v0 = v0 > 0.f ? v0 : ALPHA_ * v0;
            float v1 = acc1[r]; v1 = v1 > 0.f ? v1 : ALPHA_ * v1;
            ys[(r0 + r) * 132 + colbase + arow]      = v0;
            ys[(r0 + r) * 132 + colbase + 16 + arow] = v1;
        }
    }
    __syncthreads();

    {
        const int n  = tid >> 4;
        const int ll = tid & 15;
        float s = 0.f;
        #pragma unroll
        for (int jj = 0; jj < D_DIM; jj += 16) { const float t = ys[n * 132 + ll + jj]; s += t * t; }
        #pragma unroll
        for (int o = 8; o > 0; o >>= 1) s += __shfl_xor(s, o);
        if (ll == 0) rnorm[n] = 1.0f / fmaxf(sqrtf(s), EPS_);
    }
    __syncthreads();

    {
        const int j = tid & 127;
        const int g = tid >> 7;
        #pragma unroll
        for (int r = 0; r < 8; ++r) {
            const int n = g * 8 + r;
            const float v = ys[n * 132 + j] * rnorm[n];
            const size_t o = (size_t)(base + n) * D_DIM + j;
            if (outp != nullptr) outp[o] = v;
            if (outb != nullptr) outb[o] = f2bf(v);
            if (out8 != nullptr) out8[o] = f2fp8(v);
        }
    }
}

// ---------------------------------------------------------------------------
// fp32 fallbacks (no/small workspace)
// ---------------------------------------------------------------------------
__global__ __launch_bounds__(256)
void temporal_v8(const float* __restrict__ head,
                 const float* __restrict__ hist,
                 const float* __restrict__ Whis,
                 const float* __restrict__ WTm,
                 float* __restrict__ outp,
                 short* __restrict__ outb)
{
    __shared__ float xs[NT][2 * D_DIM];
    __shared__ float hm[NT][D_DIM];
    __shared__ float rnorm[NT];

    const int tid  = threadIdx.x;
    const int base = blockIdx.x * NT;
    const size_t HS = (size_t)NUM_P * D_DIM;

    {
        const int gp = tid >> 5;
        const int l  = tid & 31;
        for (int n = gp; n < NT; n += 8) {
            const size_t off = (size_t)(base + n) * D_DIM;
            const float4 h4 = reinterpret_cast<const float4*>(head + off)[l];
            const float4 p0 = reinterpret_cast<const float4*>(hist + off)[l];
            const float4 p1 = reinterpret_cast<const float4*>(hist + off + HS)[l];
            const float4 p2 = reinterpret_cast<const float4*>(hist + off + 2 * HS)[l];
            float4 m4;
            m4.x = (p0.x + p1.x + p2.x) * (1.0f / 3.0f);
            m4.y = (p0.y + p1.y + p2.y) * (1.0f / 3.0f);
            m4.z = (p0.z + p1.z + p2.z) * (1.0f / 3.0f);
            m4.w = (p0.w + p1.w + p2.w) * (1.0f / 3.0f);
            reinterpret_cast<float4*>(&xs[n][0])[l] = h4;
            reinterpret_cast<float4*>(&hm[n][0])[l] = m4;
        }
    }
    __syncthreads();

    const int j  = tid & 127;
    const int g  = tid >> 7;
    const int nb = g * 8;

    {
        float a2[8];
        #pragma unroll
        for (int r = 0; r < 8; ++r) a2[r] = 0.f;
        for (int c4 = 0; c4 < D_DIM / 4; ++c4) {
            const int c = c4 * 4;
            const float w0 = Whis[(size_t)(c + 0) * D_DIM + j];
            const float w1 = Whis[(size_t)(c + 1) * D_DIM + j];
            const float w2 = Whis[(size_t)(c + 2) * D_DIM + j];
            const float w3 = Whis[(size_t)(c + 3) * D_DIM + j];
            #pragma unroll
            for (int r = 0; r < 8; ++r) {
                const float4 xv = *reinterpret_cast<const float4*>(&hm[nb + r][c]);
                a2[r] = fmaf(xv.w, w3, fmaf(xv.z, w2, fmaf(xv.y, w1, fmaf(xv.x, w0, a2[r]))));
            }
        }
        __syncthreads();
        #pragma unroll
        for (int r = 0; r < 8; ++r) xs[nb + r][D_DIM + j] = a2[r];
    }
    __syncthreads();

    float acc[8];
    #pragma unroll
    for (int r = 0; r < 8; ++r) acc[r] = 0.f;
    for (int c4 = 0; c4 < (2 * D_DIM) / 4; ++c4) {
        const int c = c4 * 4;
        const float w0 = WTm[(size_t)(c + 0) * D_DIM + j];
        const float w1 = WTm[(size_t)(c + 1) * D_DIM + j];
        const float w2 = WTm[(size_t)(c + 2) * D_DIM + j];
        const float w3 = WTm[(size_t)(c + 3) * D_DIM + j];
        #pragma unroll
        for (int r = 0; r < 8; ++r) {
            const float4 xv = *reinterpret_cast<const float4*>(&xs[nb + r][c]);
            acc[r] = fmaf(xv.w, w3, fmaf(xv.z, w2, fmaf(xv.y, w1, fmaf(xv.x, w0, acc[r]))));
        }
    }
    __syncthreads();

    #pragma unroll
    for (int r = 0; r < 8; ++r) {
        float v = acc[r];
        v = v > 0.f ? v : ALPHA_ * v;
        xs[nb + r][j] = v;
    }
    __syncthreads();

    {
        const int n  = tid >> 4;
        const int ll = tid & 15;
        float s = 0.f;
        #pragma unroll
        for (int jj = ll; jj < D_DIM; jj += 16) { const float t = xs[n][jj]; s += t * t; }
        #pragma unroll
        for (int o = 8; o > 0; o >>= 1) s += __shfl_xor(s, o);
        if (ll == 0) rnorm[n] = 1.0f / fmaxf(sqrtf(s), EPS_);
    }
    __syncthreads();

    #pragma unroll
    for (int r = 0; r < 8; ++r) {
        const int n = nb + r;
        const float v = xs[n][j] * rnorm[n];
        const size_t o = (size_t)(base + n) * D_DIM + j;
        if (outp != nullptr) outp[o] = v;
        if (outb != nullptr) outb[o] = f2bf(v);
    }
}

template<int K, bool SPLIT>
__global__ __launch_bounds__(256)
void sage_v5(const float* __restrict__ srcLow,
             const float* __restrict__ srcHigh,
             const int*   __restrict__ idx,
             const float* __restrict__ W,
             float* __restrict__ out0,
             float* __restrict__ out1)
{
    __shared__ float xs[NT][2 * D_DIM];
    __shared__ int   sidx[NT * K];
    __shared__ float rnorm[NT];

    const int tid  = threadIdx.x;
    const int base = blockIdx.x * NT;

    for (int i = tid; i < NT * K; i += 256)
        sidx[i] = idx[(size_t)base * K + i];
    __syncthreads();

    {
        const int gp = tid >> 5;
        const int l  = tid & 31;
        for (int n = gp; n < NT; n += 8) {
            const int node = base + n;
            const float* sp = (!SPLIT || node < NUM_P) ? srcLow : srcHigh;
            const float4 s4 = reinterpret_cast<const float4*>(sp + (size_t)node * D_DIM)[l];
            float4 a4 = f4zero();
            for (int k = 0; k < K; ++k) {
                const int r = sidx[n * K + k];
                const float* rp = (!SPLIT || r < NUM_P) ? srcLow : srcHigh;
                const float4 v4 = reinterpret_cast<const float4*>(rp + (size_t)r * D_DIM)[l];
                a4.x += v4.x; a4.y += v4.y; a4.z += v4.z; a4.w += v4.w;
            }
            scale4(a4, 1.0f / (float)K);
            reinterpret_cast<float4*>(&xs[n][0])[l]     = s4;
            reinterpret_cast<float4*>(&xs[n][D_DIM])[l] = a4;
        }
    }
    __syncthreads();

    const int j  = tid & 127;
    const int g  = tid >> 7;
    const int nb = g * 8;

    float acc[8];
    #pragma unroll
    for (int r = 0; r < 8; ++r) acc[r] = 0.f;
    for (int c4 = 0; c4 < (2 * D_DIM) / 4; ++c4) {
        const int c = c4 * 4;
        const float w0 = W[(size_t)(c + 0) * D_DIM + j];
        const float w1 = W[(size_t)(c + 1) * D_DIM + j];
        const float w2 = W[(size_t)(c + 2) * D_DIM + j];
        const float w3 = W[(size_t)(c + 3) * D_DIM + j];
        #pragma unroll
        for (int r = 0; r < 8; ++r) {
            const float4 xv = *reinterpret_cast<const float4*>(&xs[nb + r][c]);
            acc[r] = fmaf(xv.w, w3, fmaf(xv.z, w2, fmaf(xv.y, w1, fmaf(xv.x, w0, acc[r]))));
        }
    }
    __syncthreads();

    #pragma unroll
    for (int r = 0; r < 8; ++r) {
        float v = acc[r];
        v = v > 0.f ? v : ALPHA_ * v;
        xs[nb + r][j] = v;
    }
    __syncthreads();

    {
        const int n  = tid >> 4;
        const int ll = tid & 15;
        float s = 0.f;
        #pragma unroll
        for (int jj = ll; jj < D_DIM; jj += 16) { const float t = xs[n][jj]; s += t * t; }
        #pragma unroll
        for (int o = 8; o > 0; o >>= 1) s += __shfl_xor(s, o);
        if (ll == 0) rnorm[n] = 1.0f / fmaxf(sqrtf(s), EPS_);
    }
    __syncthreads();

    #pragma unroll
    for (int r = 0; r < 8; ++r) {
        const int n    = nb + r;
        const int node = base + n;
        const float v  = xs[n][j] * rnorm[n];
        out0[(size_t)node * D_DIM + j] = v;
        if (out1 != nullptr && node >= NUM_P) out1[(size_t)node * D_DIM + j] = v;
    }
}

// ---------------------------------------------------------------------------
extern "C" void kernel_launch(void* const* d_in, const int* in_sizes, int n_in,
                              void* d_out, int out_size, void* d_ws, size_t ws_size,
                              hipStream_t stream)
{
    (void)in_sizes; (void)n_in; (void)out_size;

    const float* feats = (const float*)d_in[0];
    const int*   idx1  = (const int*)  d_in[1];
    const int*   idx2  = (const int*)  d_in[2];
    const float* hist1 = (const float*)d_in[3];
    const float* hist2 = (const float*)d_in[4];
    const float* W1    = (const float*)d_in[5];
    const float* W2    = (const float*)d_in[6];
    const float* Whis  = (const float*)d_in[7];
    const float* WTm   = (const float*)d_in[8];

    float* out = (float*)d_out;
    float* h1o = out;
    float* h2o = out + (size_t)N_NODES * D_DIM;
    float* fo  = out + 2 * (size_t)N_NODES * D_DIM;

    const int sage_blocks = N_NODES / NT;  // 3125
    const int temp_blocks = NUM_P   / NT;  // 1250

    const size_t SZ_N  = (size_t)N_NODES * D_DIM;   // 6.4M elems
    const size_t SZ_P  = (size_t)NUM_P  * D_DIM;    // 2.56M elems
    const size_t WOFF  = 114688;                     // transposed weights (shorts)
    // layout: weights | fb(bf16 N) | hb(bf16 N) | h2b(bf16 NUM) | f8(N bytes) | h8(N bytes)
    const size_t needF8 = (WOFF + 2 * SZ_N + SZ_P) * 2 + 2 * SZ_N;  // ~43.7 MB
    const size_t needA  = (WOFF + 2 * SZ_N + SZ_P) * 2;             // ~30.9 MB

    short* wsp  = (short*)d_ws;
    short* W1T  = wsp;
    short* W2T  = wsp + 32768;
    short* WhT  = wsp + 65536;
    short* WTT  = wsp + 81920;
    short* fb   = wsp + WOFF;                 // bf16 feats  [N,128]
    short* hb   = fb + SZ_N;                  // bf16 h1/f1  [N,128]
    short* h2b  = hb + SZ_N;                  // bf16 h2     [NUM_P,128]
    unsigned* f8 = (unsigned*)(h2b + SZ_P);   // fp8 feats [N,128] (N*128 bytes)
    unsigned* h8 = f8 + SZ_N / 4;             // fp8 h1/f1 [N,128]

    if (ws_size >= needF8) {
        wcvt2_kernel<<<448, 256, 0, stream>>>(W1, W2, Whis, WTm, wsp);
        fcvt8_kernel<<<(int)(SZ_N / 1024), 256, 0, stream>>>(feats, fb, f8);

        // h1: fp32 -> h1o; bf16 -> hb; fp8 -> h8 (all rows feed sage2 gather)
        sage_f8<25><<<sage_blocks, 256, 0, stream>>>(
            fb, f8, idx1, W1T, h1o, hb, N_NODES, (unsigned char*)h8, N_NODES, nullptr);
        // f1 -> hb + h8 rows [0, NUM)
        temporal_mfma<<<temp_blocks, 256, 0, stream>>>(
            hb, hist1, WhT, WTT, nullptr, hb, (unsigned char*)h8);
        // h2: fp32 -> h2o; bf16 rows<NUM -> h2b; fp32 tail -> fo
        sage_f8<10><<<sage_blocks, 256, 0, stream>>>(
            hb, h8, idx2, W2T, h2o, h2b, NUM_P, nullptr, 0, fo);
        // f2 -> fo rows [0, NUM)
        temporal_mfma<<<temp_blocks, 256, 0, stream>>>(
            h2b, hist2, WhT, WTT, fo, nullptr, nullptr);
    } else if (ws_size >= needA) {
        wcvt2_kernel<<<448, 256, 0, stream>>>(W1, W2, Whis, WTm, wsp);
        fcvt_kernel<<<(int)(SZ_N / 1024), 256, 0, stream>>>(feats, fb);

        sage_mfma8<25><<<sage_blocks, 256, 0, stream>>>(fb, idx1, W1T, h1o, hb, N_NODES, nullptr);
        temporal_mfma<<<temp_blocks, 256, 0, stream>>>(hb, hist1, WhT, WTT, nullptr, hb, nullptr);
        sage_mfma8<10><<<sage_blocks, 256, 0, stream>>>(hb, idx2, W2T, h2o, h2b, NUM_P, fo);
        temporal_mfma<<<temp_blocks, 256, 0, stream>>>(h2b, hist2, WhT, WTT, fo, nullptr, nullptr);
    } else {
        sage_v5<25, false><<<sage_blocks, 256, 0, stream>>>(feats, feats, idx1, W1, h1o, nullptr);
        temporal_v8<<<temp_blocks, 256, 0, stream>>>(h1o, hist1, Whis, WTm, fo, nullptr);
        sage_v5<10, true><<<sage_blocks, 256, 0, stream>>>(fo, h1o, idx2, W2, h2o, fo);
        temporal_v8<<<temp_blocks, 256, 0, stream>>>(h2o, hist2, Whis, WTm, fo, nullptr);
    }
}

// Round 16
// 132.689 us; speedup vs baseline: 1.3667x; 1.0591x over previous
//
#include <hip/hip_runtime.h>
#include <hip/hip_bf16.h>

#define N_NODES 50000
#define NUM_P   20000
#define D_DIM   128
#define ALPHA_  0.2f
#define EPS_    1e-12f
#define NT      16      // nodes per tile (50000 = 3125*16, 20000 = 1250*16)

typedef __attribute__((ext_vector_type(8))) short bf16x8;
typedef __attribute__((ext_vector_type(4))) float f32x4;
typedef __attribute__((ext_vector_type(2))) float f32x2;

#if defined(__has_builtin)
#if __has_builtin(__builtin_amdgcn_cvt_pk_f32_fp8) && __has_builtin(__builtin_amdgcn_cvt_pk_fp8_f32)
#define HAVE_HW_FP8 1
#endif
#endif

__device__ __forceinline__ float4 f4zero() { return make_float4(0.f, 0.f, 0.f, 0.f); }

__device__ __forceinline__ void scale4(float4& v, const float s) {
    v.x *= s; v.y *= s; v.z *= s; v.w *= s;
}

__device__ __forceinline__ short f2bf(float f) {
    __hip_bfloat16 h = __float2bfloat16(f);
    return *reinterpret_cast<short*>(&h);
}

__device__ __forceinline__ float bf2f(short u) {
    union { unsigned i; float f; } c;
    c.i = ((unsigned)(unsigned short)u) << 16;
    return c.f;
}

__device__ __forceinline__ short4 pack4(const float4 v) {
    short4 s;
    s.x = f2bf(v.x); s.y = f2bf(v.y); s.z = f2bf(v.z); s.w = f2bf(v.w);
    return s;
}

// ---------------- fp8 e4m3 helpers (HW cvt on gfx950, SW fallback) ----------
__device__ __forceinline__ float fp8_sw_dec(unsigned b) {
    unsigned e = (b >> 3) & 0xF, m = b & 7;
    float v = (e == 0) ? (float)m * 0.001953125f
                       : __uint_as_float(((e + 120u) << 23) | (m << 20));
    return (b & 0x80) ? -v : v;
}

__device__ __forceinline__ unsigned fp8_sw_enc(float f) {
    unsigned s = f < 0.f ? 0x80u : 0u;
    float af = fabsf(f);
    if (af >= 448.f) return s | 0x7E;
    if (af < 0.0009765625f) return s;
    int e; float m = frexpf(af, &e);
    int E = e - 1;
    if (E < -6) {
        int q = (int)rintf(af * 512.f);
        if (q >= 8) return s | 0x08;
        return s | (unsigned)q;
    }
    int q = (int)rintf(m * 16.f);
    if (q == 16) { q = 8; ++E; }
    if (E > 8) return s | 0x7E;
    return s | ((unsigned)(E + 7) << 3) | (unsigned)(q - 8);
}

template<bool HI>
__device__ __forceinline__ f32x2 fp8x2_dec(unsigned v) {
#ifdef HAVE_HW_FP8
    return __builtin_amdgcn_cvt_pk_f32_fp8((int)v, HI);
#else
    f32x2 r;
    unsigned b0 = HI ? ((v >> 16) & 0xFF) : (v & 0xFF);
    unsigned b1 = HI ? (v >> 24)          : ((v >> 8) & 0xFF);
    r[0] = fp8_sw_dec(b0); r[1] = fp8_sw_dec(b1);
    return r;
#endif
}

__device__ __forceinline__ unsigned char f2fp8(float v) {
#ifdef HAVE_HW_FP8
    return (unsigned char)(__builtin_amdgcn_cvt_pk_fp8_f32(v, v, 0, false) & 0xFF);
#else
    return (unsigned char)fp8_sw_enc(v);
#endif
}

__device__ __forceinline__ unsigned pack4_fp8(const float4 v) {
#ifdef HAVE_HW_FP8
    int lo = __builtin_amdgcn_cvt_pk_fp8_f32(v.x, v.y, 0, false);
    return (unsigned)__builtin_amdgcn_cvt_pk_fp8_f32(v.z, v.w, lo, true);
#else
    return fp8_sw_enc(v.x) | (fp8_sw_enc(v.y) << 8) |
           (fp8_sw_enc(v.z) << 16) | (fp8_sw_enc(v.w) << 24);
#endif
}

// ---------------------------------------------------------------------------
// Merged convert: blocks [0,448) transpose weights to bf16; blocks [448,...)
// mirror feats to bf16 + fp8.
// ---------------------------------------------------------------------------
__global__ __launch_bounds__(256)
void cvt_all_kernel(const float* __restrict__ W1, const float* __restrict__ W2,
                    const float* __restrict__ Whis, const float* __restrict__ WTm,
                    short* __restrict__ ow,
                    const float* __restrict__ feats, short* __restrict__ ob,
                    unsigned* __restrict__ o8)
{
    if (blockIdx.x < 448) {
        const int i = blockIdx.x * 256 + threadIdx.x;   // 0..114687
        float v;
        if (i < 65536) {
            const float* W = (i < 32768) ? W1 : W2;
            const int t = i & 32767;
            v = W[(size_t)(t & 255) * D_DIM + (t >> 8)];
        } else if (i < 81920) {
            const int t = i - 65536;
            v = Whis[(size_t)(t & 127) * D_DIM + (t >> 7)];
        } else {
            const int t = i - 81920;
            v = WTm[(size_t)(t & 255) * D_DIM + (t >> 8)];
        }
        ow[i] = f2bf(v);
    } else {
        const int i = (blockIdx.x - 448) * 256 + threadIdx.x;   // float4 index
        const float4 v = reinterpret_cast<const float4*>(feats)[i];
        reinterpret_cast<short4*>(ob)[i] = pack4(v);
        o8[i] = pack4_fp8(v);
    }
}

// fp32 -> bf16 mirror only (fallback path)
__global__ __launch_bounds__(256)
void fcvt_kernel(const float* __restrict__ in, short* __restrict__ ob)
{
    const int i = blockIdx.x * 256 + threadIdx.x;
    const float4 v = reinterpret_cast<const float4*>(in)[i];
    reinterpret_cast<short4*>(ob)[i] = pack4(v);
}

// ---------------------------------------------------------------------------
// Fused MFMA SAGE, fp8 neighbor gather, 16-lanes-per-row (8B/lane uint2):
//   srcB bf16 [*,128] (self rows), src8 fp8 [*,128] (neighbor rows).
// ---------------------------------------------------------------------------
template<int K>
__global__ __launch_bounds__(256)
void sage_f8(const short*    __restrict__ srcB,
             const unsigned* __restrict__ src8,
             const int*      __restrict__ idx,
             const short*    __restrict__ WTg,     // [128][256] bf16 = W transposed
             float* __restrict__ out0,
             short* __restrict__ outb, int nb_limit,
             unsigned char* __restrict__ out8, int n8_limit,
             float* __restrict__ out1)
{
    __shared__ __align__(16) char uni[NT * 132 * 4];
    __shared__ float rnorm[NT];
    __shared__ int   sidx[NT * K];
    short* xs = reinterpret_cast<short*>(uni);   // [n][256] bf16, swizzled
    float* ys = reinterpret_cast<float*>(uni);   // [n][132] fp32

    const int tid  = threadIdx.x;
    const int base = blockIdx.x * NT;

    for (int i = tid; i < NT * K; i += 256)
        sidx[i] = idx[(size_t)base * K + i];
    __syncthreads();

    // ---- gather: 16 lanes per row; one node per 16-lane group ----
    {
        const int n = tid >> 4;     // node 0..15
        const int l = tid & 15;     // lane in group
        const int node = base + n;
        const int swzn = (n & 7) << 3;

        // self: 16B/lane bf16
        const int4 s8 = reinterpret_cast<const int4*>(srcB + (size_t)node * D_DIM)[l];

        float a0 = 0.f, a1 = 0.f, a2 = 0.f, a3 = 0.f;
        float a4 = 0.f, a5 = 0.f, a6 = 0.f, a7 = 0.f;
        for (int k = 0; k < K; ++k) {
            const int r = sidx[n * K + k];
            const uint2 v = *reinterpret_cast<const uint2*>(src8 + (size_t)r * 32 + l * 2);
            const f32x2 p0 = fp8x2_dec<false>(v.x);
            const f32x2 p1 = fp8x2_dec<true>(v.x);
            const f32x2 p2 = fp8x2_dec<false>(v.y);
            const f32x2 p3 = fp8x2_dec<true>(v.y);
            a0 += p0[0]; a1 += p0[1]; a2 += p1[0]; a3 += p1[1];
            a4 += p2[0]; a5 += p2[1]; a6 += p3[0]; a7 += p3[1];
        }
        const float s = 1.0f / (float)K;
        short m8[8];
        m8[0] = f2bf(a0 * s); m8[1] = f2bf(a1 * s); m8[2] = f2bf(a2 * s); m8[3] = f2bf(a3 * s);
        m8[4] = f2bf(a4 * s); m8[5] = f2bf(a5 * s); m8[6] = f2bf(a6 * s); m8[7] = f2bf(a7 * s);

        *reinterpret_cast<int4*>(&xs[n * 256 + ((l * 8) ^ swzn)])         = s8;
        *reinterpret_cast<int4*>(&xs[n * 256 + ((D_DIM + l * 8) ^ swzn)]) = *reinterpret_cast<int4*>(m8);
    }
    __syncthreads();

    // ---- MFMA: wave w -> cols [32w, 32w+32), K=256 in 8 steps ----
    const int w    = tid >> 6;
    const int l    = tid & 63;
    const int arow = l & 15;
    const int kg   = l >> 4;
    const int swz  = (arow & 7) << 3;

    f32x4 acc0 = {0.f, 0.f, 0.f, 0.f};
    f32x4 acc1 = {0.f, 0.f, 0.f, 0.f};
    const int colbase = w * 32;
    const short* b0 = WTg + (size_t)(colbase + arow) * 256 + kg * 8;
    const short* b1 = b0 + 16 * 256;

    #pragma unroll
    for (int step = 0; step < 8; ++step) {
        const int aoff = arow * 256 + ((step * 32 + kg * 8) ^ swz);
        const bf16x8 av  = *reinterpret_cast<const bf16x8*>(&xs[aoff]);
        const bf16x8 bv0 = *reinterpret_cast<const bf16x8*>(b0 + step * 32);
        const bf16x8 bv1 = *reinterpret_cast<const bf16x8*>(b1 + step * 32);
        acc0 = __builtin_amdgcn_mfma_f32_16x16x32_bf16(av, bv0, acc0, 0, 0, 0);
        acc1 = __builtin_amdgcn_mfma_f32_16x16x32_bf16(av, bv1, acc1, 0, 0, 0);
    }
    __syncthreads();

    // ---- epilogue: leaky -> ys (D layout: node=(l>>4)*4+r, col-local=l&15)
    {
        const int r0 = kg * 4;
        #pragma unroll
        for (int r = 0; r < 4; ++r) {
            float v0 = acc0[r]; v0 = v0 > 0.f ? v0 : ALPHA_ * v0;
            float v1 = acc1[r]; v1 = v1 > 0.f ? v1 : ALPHA_ * v1;
            ys[(r0 + r) * 132 + colbase + arow]      = v0;
            ys[(r0 + r) * 132 + colbase + 16 + arow] = v1;
        }
    }
    __syncthreads();

    {
        const int n  = tid >> 4;
        const int ll = tid & 15;
        float s = 0.f;
        #pragma unroll
        for (int jj = 0; jj < D_DIM; jj += 16) { const float t = ys[n * 132 + ll + jj]; s += t * t; }
        #pragma unroll
        for (int o = 8; o > 0; o >>= 1) s += __shfl_xor(s, o);
        if (ll == 0) rnorm[n] = 1.0f / fmaxf(sqrtf(s), EPS_);
    }
    __syncthreads();

    {
        const int j = tid & 127;
        const int g = tid >> 7;
        #pragma unroll
        for (int r = 0; r < 8; ++r) {
            const int n    = g * 8 + r;
            const int node = base + n;
            const float v  = ys[n * 132 + j] * rnorm[n];
            out0[(size_t)node * D_DIM + j] = v;
            if (outb != nullptr && node < nb_limit) outb[(size_t)node * D_DIM + j] = f2bf(v);
            if (out8 != nullptr && node < n8_limit) out8[(size_t)node * D_DIM + j] = f2fp8(v);
            if (out1 != nullptr && node >= NUM_P)   out1[(size_t)node * D_DIM + j] = v;
        }
    }
}

// ---------------------------------------------------------------------------
// Fused MFMA SAGE, bf16 gather (round-10 proven; fallback)
// ---------------------------------------------------------------------------
template<int K>
__global__ __launch_bounds__(256)
void sage_mfma8(const short* __restrict__ src,
                const int*   __restrict__ idx,
                const short* __restrict__ WTg,
                float* __restrict__ out0,
                short* __restrict__ outb,
                int nb_limit,
                float* __restrict__ out1)
{
    __shared__ __align__(16) char uni[NT * 132 * 4];
    __shared__ float rnorm[NT];
    __shared__ int   sidx[NT * K];
    short* xs = reinterpret_cast<short*>(uni);
    float* ys = reinterpret_cast<float*>(uni);

    const int tid  = threadIdx.x;
    const int base = blockIdx.x * NT;

    for (int i = tid; i < NT * K; i += 256)
        sidx[i] = idx[(size_t)base * K + i];
    __syncthreads();

    {
        const int gp = tid >> 5;
        const int l  = tid & 31;
        for (int n = gp; n < NT; n += 8) {
            const int node = base + n;
            const short4 s4 = reinterpret_cast<const short4*>(src + (size_t)node * D_DIM)[l];
            float4 a4 = f4zero();
            for (int k = 0; k < K; ++k) {
                const int r = sidx[n * K + k];
                const short4 v4 = reinterpret_cast<const short4*>(src + (size_t)r * D_DIM)[l];
                a4.x += bf2f(v4.x); a4.y += bf2f(v4.y);
                a4.z += bf2f(v4.z); a4.w += bf2f(v4.w);
            }
            scale4(a4, 1.0f / (float)K);
            const int swzn = (n & 7) << 3;
            *reinterpret_cast<short4*>(&xs[n * 256 + ((l * 4) ^ swzn)])         = s4;
            *reinterpret_cast<short4*>(&xs[n * 256 + ((D_DIM + l * 4) ^ swzn)]) = pack4(a4);
        }
    }
    __syncthreads();

    const int w    = tid >> 6;
    const int l    = tid & 63;
    const int arow = l & 15;
    const int kg   = l >> 4;
    const int swz  = (arow & 7) << 3;

    f32x4 acc0 = {0.f, 0.f, 0.f, 0.f};
    f32x4 acc1 = {0.f, 0.f, 0.f, 0.f};
    const int colbase = w * 32;
    const short* b0 = WTg + (size_t)(colbase + arow) * 256 + kg * 8;
    const short* b1 = b0 + 16 * 256;

    #pragma unroll
    for (int step = 0; step < 8; ++step) {
        const int aoff = arow * 256 + ((step * 32 + kg * 8) ^ swz);
        const bf16x8 av  = *reinterpret_cast<const bf16x8*>(&xs[aoff]);
        const bf16x8 bv0 = *reinterpret_cast<const bf16x8*>(b0 + step * 32);
        const bf16x8 bv1 = *reinterpret_cast<const bf16x8*>(b1 + step * 32);
        acc0 = __builtin_amdgcn_mfma_f32_16x16x32_bf16(av, bv0, acc0, 0, 0, 0);
        acc1 = __builtin_amdgcn_mfma_f32_16x16x32_bf16(av, bv1, acc1, 0, 0, 0);
    }
    __syncthreads();

    {
        const int r0 = kg * 4;
        #pragma unroll
        for (int r = 0; r < 4; ++r) {
            float v0 = acc0[r]; v0 = v0 > 0.f ? v0 : ALPHA_ * v0;
            float v1 = acc1[r]; v1 = v1 > 0.f ? v1 : ALPHA_ * v1;
            ys[(r0 + r) * 132 + colbase + arow]      = v0;
            ys[(r0 + r) * 132 + colbase + 16 + arow] = v1;
        }
    }
    __syncthreads();

    {
        const int n  = tid >> 4;
        const int ll = tid & 15;
        float s = 0.f;
        #pragma unroll
        for (int jj = 0; jj < D_DIM; jj += 16) { const float t = ys[n * 132 + ll + jj]; s += t * t; }
        #pragma unroll
        for (int o = 8; o > 0; o >>= 1) s += __shfl_xor(s, o);
        if (ll == 0) rnorm[n] = 1.0f / fmaxf(sqrtf(s), EPS_);
    }
    __syncthreads();

    {
        const int j = tid & 127;
        const int g = tid >> 7;
        #pragma unroll
        for (int r = 0; r < 8; ++r) {
            const int n    = g * 8 + r;
            const int node = base + n;
            const float v  = ys[n * 132 + j] * rnorm[n];
            out0[(size_t)node * D_DIM + j] = v;
            if (outb != nullptr && node < nb_limit) outb[(size_t)node * D_DIM + j] = f2bf(v);
            if (out1 != nullptr && node >= NUM_P)   out1[(size_t)node * D_DIM + j] = v;
        }
    }
}

// ---------------------------------------------------------------------------
// MFMA temporal (round-9 proven). headb/outb/out8 may alias headb's table
// (per-row read-then-write within the owning block only).
// ---------------------------------------------------------------------------
__global__ __launch_bounds__(256)
void temporal_mfma(const short* headb,
                   const float* __restrict__ hist,
                   const short* __restrict__ WhisTg,
                   const short* __restrict__ WTTg,
                   float* __restrict__ outp,
                   short* outb,
                   unsigned char* out8)
{
    __shared__ __align__(16) char uni[NT * 132 * 4];
    __shared__ float rnorm[NT];
    short* xs = reinterpret_cast<short*>(uni);
    float* ys = reinterpret_cast<float*>(uni);

    const int tid  = threadIdx.x;
    const int base = blockIdx.x * NT;
    const size_t HS = (size_t)NUM_P * D_DIM;

    {
        const int gp = tid >> 5;
        const int l  = tid & 31;
        for (int n = gp; n < NT; n += 8) {
            const size_t off = (size_t)(base + n) * D_DIM;
            const short4 h4 = reinterpret_cast<const short4*>(headb + off)[l];
            const float4 p0 = reinterpret_cast<const float4*>(hist + off)[l];
            const float4 p1 = reinterpret_cast<const float4*>(hist + off + HS)[l];
            const float4 p2 = reinterpret_cast<const float4*>(hist + off + 2 * HS)[l];
            float4 m4;
            m4.x = (p0.x + p1.x + p2.x) * (1.0f / 3.0f);
            m4.y = (p0.y + p1.y + p2.y) * (1.0f / 3.0f);
            m4.z = (p0.z + p1.z + p2.z) * (1.0f / 3.0f);
            m4.w = (p0.w + p1.w + p2.w) * (1.0f / 3.0f);
            const int swzn = (n & 7) << 3;
            *reinterpret_cast<short4*>(&xs[n * 256 + ((l * 4) ^ swzn)])         = h4;
            *reinterpret_cast<short4*>(&xs[n * 256 + ((D_DIM + l * 4) ^ swzn)]) = pack4(m4);
        }
    }
    __syncthreads();

    const int w    = tid >> 6;
    const int l    = tid & 63;
    const int arow = l & 15;
    const int kg   = l >> 4;
    const int swz  = (arow & 7) << 3;
    const int colbase = w * 32;

    {
        f32x4 t0 = {0.f, 0.f, 0.f, 0.f};
        f32x4 t1 = {0.f, 0.f, 0.f, 0.f};
        const short* b0 = WhisTg + (size_t)(colbase + arow) * 128 + kg * 8;
        const short* b1 = b0 + 16 * 128;
        #pragma unroll
        for (int step = 0; step < 4; ++step) {
            const int aoff = arow * 256 + ((D_DIM + step * 32 + kg * 8) ^ swz);
            const bf16x8 av  = *reinterpret_cast<const bf16x8*>(&xs[aoff]);
            const bf16x8 bv0 = *reinterpret_cast<const bf16x8*>(b0 + step * 32);
            const bf16x8 bv1 = *reinterpret_cast<const bf16x8*>(b1 + step * 32);
            t0 = __builtin_amdgcn_mfma_f32_16x16x32_bf16(av, bv0, t0, 0, 0, 0);
            t1 = __builtin_amdgcn_mfma_f32_16x16x32_bf16(av, bv1, t1, 0, 0, 0);
        }
        __syncthreads();

        #pragma unroll
        for (int r = 0; r < 4; ++r) {
            const int node = kg * 4 + r;
            const int swzn = (node & 7) << 3;
            xs[node * 256 + ((D_DIM + colbase + arow) ^ swzn)]      = f2bf(t0[r]);
            xs[node * 256 + ((D_DIM + colbase + 16 + arow) ^ swzn)] = f2bf(t1[r]);
        }
    }
    __syncthreads();

    f32x4 acc0 = {0.f, 0.f, 0.f, 0.f};
    f32x4 acc1 = {0.f, 0.f, 0.f, 0.f};
    {
        const short* b0 = WTTg + (size_t)(colbase + arow) * 256 + kg * 8;
        const short* b1 = b0 + 16 * 256;
        #pragma unroll
        for (int step = 0; step < 8; ++step) {
            const int aoff = arow * 256 + ((step * 32 + kg * 8) ^ swz);
            const bf16x8 av  = *reinterpret_cast<const bf16x8*>(&xs[aoff]);
            const bf16x8 bv0 = *reinterpret_cast<const bf16x8*>(b0 + step * 32);
            const bf16x8 bv1 = *reinterpret_cast<const bf16x8*>(b1 + step * 32);
            acc0 = __builtin_amdgcn_mfma_f32_16x16x32_bf16(av, bv0, acc0, 0, 0, 0);
            acc1 = __builtin_amdgcn_mfma_f32_16x16x32_bf16(av, bv1, acc1, 0, 0, 0);
        }
    }
    __syncthreads();

    {
        const int r0 = kg * 4;
        #pragma unroll
        for (int r = 0; r < 4; ++r) {
            float v0 = acc0[r]; v0 = v0 > 0.f ? v0 : ALPHA_ * v0;
            float v1 = acc1[r]; v1 = v1 > 0.f ? v1 : ALPHA_ * v1;
            ys[(r0 + r) * 132 + colbase + arow]      = v0;
            ys[(r0 + r) * 132 + colbase + 16 + arow] = v1;
        }
    }
    __syncthreads();

    {
        const int n  = tid >> 4;
        const int ll = tid & 15;
        float s = 0.f;
        #pragma unroll
        for (int jj = 0; jj < D_DIM; jj += 16) { const float t = ys[n * 132 + ll + jj]; s += t * t; }
        #pragma unroll
        for (int o = 8; o > 0; o >>= 1) s += __shfl_xor(s, o);
        if (ll == 0) rnorm[n] = 1.0f / fmaxf(sqrtf(s), EPS_);
    }
    __syncthreads();

    {
        const int j = tid & 127;
        const int g = tid >> 7;
        #pragma unroll
        for (int r = 0; r < 8; ++r) {
            const int n = g * 8 + r;
            const float v = ys[n * 132 + j] * rnorm[n];
            const size_t o = (size_t)(base + n) * D_DIM + j;
            if (outp != nullptr) outp[o] = v;
            if (outb != nullptr) outb[o] = f2bf(v);
            if (out8 != nullptr) out8[o] = f2fp8(v);
        }
    }
}

// ---------------------------------------------------------------------------
// fp32 fallbacks (no/small workspace)
// ---------------------------------------------------------------------------
__global__ __launch_bounds__(256)
void temporal_v8(const float* __restrict__ head,
                 const float* __restrict__ hist,
                 const float* __restrict__ Whis,
                 const float* __restrict__ WTm,
                 float* __restrict__ outp,
                 short* __restrict__ outb)
{
    __shared__ float xs[NT][2 * D_DIM];
    __shared__ float hm[NT][D_DIM];
    __shared__ float rnorm[NT];

    const int tid  = threadIdx.x;
    const int base = blockIdx.x * NT;
    const size_t HS = (size_t)NUM_P * D_DIM;

    {
        const int gp = tid >> 5;
        const int l  = tid & 31;
        for (int n = gp; n < NT; n += 8) {
            const size_t off = (size_t)(base + n) * D_DIM;
            const float4 h4 = reinterpret_cast<const float4*>(head + off)[l];
            const float4 p0 = reinterpret_cast<const float4*>(hist + off)[l];
            const float4 p1 = reinterpret_cast<const float4*>(hist + off + HS)[l];
            const float4 p2 = reinterpret_cast<const float4*>(hist + off + 2 * HS)[l];
            float4 m4;
            m4.x = (p0.x + p1.x + p2.x) * (1.0f / 3.0f);
            m4.y = (p0.y + p1.y + p2.y) * (1.0f / 3.0f);
            m4.z = (p0.z + p1.z + p2.z) * (1.0f / 3.0f);
            m4.w = (p0.w + p1.w + p2.w) * (1.0f / 3.0f);
            reinterpret_cast<float4*>(&xs[n][0])[l] = h4;
            reinterpret_cast<float4*>(&hm[n][0])[l] = m4;
        }
    }
    __syncthreads();

    const int j  = tid & 127;
    const int g  = tid >> 7;
    const int nb = g * 8;

    {
        float a2[8];
        #pragma unroll
        for (int r = 0; r < 8; ++r) a2[r] = 0.f;
        for (int c4 = 0; c4 < D_DIM / 4; ++c4) {
            const int c = c4 * 4;
            const float w0 = Whis[(size_t)(c + 0) * D_DIM + j];
            const float w1 = Whis[(size_t)(c + 1) * D_DIM + j];
            const float w2 = Whis[(size_t)(c + 2) * D_DIM + j];
            const float w3 = Whis[(size_t)(c + 3) * D_DIM + j];
            #pragma unroll
            for (int r = 0; r < 8; ++r) {
                const float4 xv = *reinterpret_cast<const float4*>(&hm[nb + r][c]);
                a2[r] = fmaf(xv.w, w3, fmaf(xv.z, w2, fmaf(xv.y, w1, fmaf(xv.x, w0, a2[r]))));
            }
        }
        __syncthreads();
        #pragma unroll
        for (int r = 0; r < 8; ++r) xs[nb + r][D_DIM + j] = a2[r];
    }
    __syncthreads();

    float acc[8];
    #pragma unroll
    for (int r = 0; r < 8; ++r) acc[r] = 0.f;
    for (int c4 = 0; c4 < (2 * D_DIM) / 4; ++c4) {
        const int c = c4 * 4;
        const float w0 = WTm[(size_t)(c + 0) * D_DIM + j];
        const float w1 = WTm[(size_t)(c + 1) * D_DIM + j];
        const float w2 = WTm[(size_t)(c + 2) * D_DIM + j];
        const float w3 = WTm[(size_t)(c + 3) * D_DIM + j];
        #pragma unroll
        for (int r = 0; r < 8; ++r) {
            const float4 xv = *reinterpret_cast<const float4*>(&xs[nb + r][c]);
            acc[r] = fmaf(xv.w, w3, fmaf(xv.z, w2, fmaf(xv.y, w1, fmaf(xv.x, w0, acc[r]))));
        }
    }
    __syncthreads();

    #pragma unroll
    for (int r = 0; r < 8; ++r) {
        float v = acc[r];
        v = v > 0.f ? v : ALPHA_ * v;
        xs[nb + r][j] = v;
    }
    __syncthreads();

    {
        const int n  = tid >> 4;
        const int ll = tid & 15;
        float s = 0.f;
        #pragma unroll
        for (int jj = ll; jj < D_DIM; jj += 16) { const float t = xs[n][jj]; s += t * t; }
        #pragma unroll
        for (int o = 8; o > 0; o >>= 1) s += __shfl_xor(s, o);
        if (ll == 0) rnorm[n] = 1.0f / fmaxf(sqrtf(s), EPS_);
    }
    __syncthreads();

    #pragma unroll
    for (int r = 0; r < 8; ++r) {
        const int n = nb + r;
        const float v = xs[n][j] * rnorm[n];
        const size_t o = (size_t)(base + n) * D_DIM + j;
        if (outp != nullptr) outp[o] = v;
        if (outb != nullptr) outb[o] = f2bf(v);
    }
}

template<int K, bool SPLIT>
__global__ __launch_bounds__(256)
void sage_v5(const float* __restrict__ srcLow,
             const float* __restrict__ srcHigh,
             const int*   __restrict__ idx,
             const float* __restrict__ W,
             float* __restrict__ out0,
             float* __restrict__ out1)
{
    __shared__ float xs[NT][2 * D_DIM];
    __shared__ int   sidx[NT * K];
    __shared__ float rnorm[NT];

    const int tid  = threadIdx.x;
    const int base = blockIdx.x * NT;

    for (int i = tid; i < NT * K; i += 256)
        sidx[i] = idx[(size_t)base * K + i];
    __syncthreads();

    {
        const int gp = tid >> 5;
        const int l  = tid & 31;
        for (int n = gp; n < NT; n += 8) {
            const int node = base + n;
            const float* sp = (!SPLIT || node < NUM_P) ? srcLow : srcHigh;
            const float4 s4 = reinterpret_cast<const float4*>(sp + (size_t)node * D_DIM)[l];
            float4 a4 = f4zero();
            for (int k = 0; k < K; ++k) {
                const int r = sidx[n * K + k];
                const float* rp = (!SPLIT || r < NUM_P) ? srcLow : srcHigh;
                const float4 v4 = reinterpret_cast<const float4*>(rp + (size_t)r * D_DIM)[l];
                a4.x += v4.x; a4.y += v4.y; a4.z += v4.z; a4.w += v4.w;
            }
            scale4(a4, 1.0f / (float)K);
            reinterpret_cast<float4*>(&xs[n][0])[l]     = s4;
            reinterpret_cast<float4*>(&xs[n][D_DIM])[l] = a4;
        }
    }
    __syncthreads();

    const int j  = tid & 127;
    const int g  = tid >> 7;
    const int nb = g * 8;

    float acc[8];
    #pragma unroll
    for (int r = 0; r < 8; ++r) acc[r] = 0.f;
    for (int c4 = 0; c4 < (2 * D_DIM) / 4; ++c4) {
        const int c = c4 * 4;
        const float w0 = W[(size_t)(c + 0) * D_DIM + j];
        const float w1 = W[(size_t)(c + 1) * D_DIM + j];
        const float w2 = W[(size_t)(c + 2) * D_DIM + j];
        const float w3 = W[(size_t)(c + 3) * D_DIM + j];
        #pragma unroll
        for (int r = 0; r < 8; ++r) {
            const float4 xv = *reinterpret_cast<const float4*>(&xs[nb + r][c]);
            acc[r] = fmaf(xv.w, w3, fmaf(xv.z, w2, fmaf(xv.y, w1, fmaf(xv.x, w0, acc[r]))));
        }
    }
    __syncthreads();

    #pragma unroll
    for (int r = 0; r < 8; ++r) {
        float v = acc[r];
        v = v > 0.f ? v : ALPHA_ * v;
        xs[nb + r][j] = v;
    }
    __syncthreads();

    {
        const int n  = tid >> 4;
        const int ll = tid & 15;
        float s = 0.f;
        #pragma unroll
        for (int jj = ll; jj < D_DIM; jj += 16) { const float t = xs[n][jj]; s += t * t; }
        #pragma unroll
        for (int o = 8; o > 0; o >>= 1) s += __shfl_xor(s, o);
        if (ll == 0) rnorm[n] = 1.0f / fmaxf(sqrtf(s), EPS_);
    }
    __syncthreads();

    #pragma unroll
    for (int r = 0; r < 8; ++r) {
        const int n    = nb + r;
        const int node = base + n;
        const float v  = xs[n][j] * rnorm[n];
        out0[(size_t)node * D_DIM + j] = v;
        if (out1 != nullptr && node >= NUM_P) out1[(size_t)node * D_DIM + j] = v;
    }
}

// ---------------------------------------------------------------------------
extern "C" void kernel_launch(void* const* d_in, const int* in_sizes, int n_in,
                              void* d_out, int out_size, void* d_ws, size_t ws_size,
                              hipStream_t stream)
{
    (void)in_sizes; (void)n_in; (void)out_size;

    const float* feats = (const float*)d_in[0];
    const int*   idx1  = (const int*)  d_in[1];
    const int*   idx2  = (const int*)  d_in[2];
    const float* hist1 = (const float*)d_in[3];
    const float* hist2 = (const float*)d_in[4];
    const float* W1    = (const float*)d_in[5];
    const float* W2    = (const float*)d_in[6];
    const float* Whis  = (const float*)d_in[7];
    const float* WTm   = (const float*)d_in[8];

    float* out = (float*)d_out;
    float* h1o = out;
    float* h2o = out + (size_t)N_NODES * D_DIM;
    float* fo  = out + 2 * (size_t)N_NODES * D_DIM;

    const int sage_blocks = N_NODES / NT;  // 3125
    const int temp_blocks = NUM_P   / NT;  // 1250

    const size_t SZ_N  = (size_t)N_NODES * D_DIM;   // 6.4M elems
    const size_t SZ_P  = (size_t)NUM_P  * D_DIM;    // 2.56M elems
    const size_t WOFF  = 114688;                     // transposed weights (shorts)
    // layout: weights | fb(bf16 N) | hb(bf16 N) | h2b(bf16 NUM) | f8(N bytes) | h8(N bytes)
    const size_t needF8 = (WOFF + 2 * SZ_N + SZ_P) * 2 + 2 * SZ_N;  // ~43.7 MB
    const size_t needA  = (WOFF + 2 * SZ_N + SZ_P) * 2;             // ~30.9 MB

    short* wsp  = (short*)d_ws;
    short* W1T  = wsp;
    short* W2T  = wsp + 32768;
    short* WhT  = wsp + 65536;
    short* WTT  = wsp + 81920;
    short* fb   = wsp + WOFF;                 // bf16 feats  [N,128]
    short* hb   = fb + SZ_N;                  // bf16 h1/f1  [N,128]
    short* h2b  = hb + SZ_N;                  // bf16 h2     [NUM_P,128]
    unsigned* f8 = (unsigned*)(h2b + SZ_P);   // fp8 feats [N,128] (N*128 bytes)
    unsigned* h8 = f8 + SZ_N / 4;             // fp8 h1/f1 [N,128]

    if (ws_size >= needF8) {
        // merged weight-transpose + feats bf16/fp8 mirror: 448 + 6250 blocks
        cvt_all_kernel<<<448 + (int)(SZ_N / 1024), 256, 0, stream>>>(
            W1, W2, Whis, WTm, wsp, feats, fb, f8);

        // h1: fp32 -> h1o; bf16 -> hb; fp8 -> h8 (all rows feed sage2 gather)
        sage_f8<25><<<sage_blocks, 256, 0, stream>>>(
            fb, f8, idx1, W1T, h1o, hb, N_NODES, (unsigned char*)h8, N_NODES, nullptr);
        // f1 -> hb + h8 rows [0, NUM)
        temporal_mfma<<<temp_blocks, 256, 0, stream>>>(
            hb, hist1, WhT, WTT, nullptr, hb, (unsigned char*)h8);
        // h2: fp32 -> h2o; bf16 rows<NUM -> h2b; fp32 tail -> fo
        sage_f8<10><<<sage_blocks, 256, 0, stream>>>(
            hb, h8, idx2, W2T, h2o, h2b, NUM_P, nullptr, 0, fo);
        // f2 -> fo rows [0, NUM)
        temporal_mfma<<<temp_blocks, 256, 0, stream>>>(
            h2b, hist2, WhT, WTT, fo, nullptr, nullptr);
    } else if (ws_size >= needA) {
        cvt_all_kernel<<<448, 256, 0, stream>>>(W1, W2, Whis, WTm, wsp, feats, fb, f8);
        fcvt_kernel<<<(int)(SZ_N / 1024), 256, 0, stream>>>(feats, fb);

        sage_mfma8<25><<<sage_blocks, 256, 0, stream>>>(fb, idx1, W1T, h1o, hb, N_NODES, nullptr);
        temporal_mfma<<<temp_blocks, 256, 0, stream>>>(hb, hist1, WhT, WTT, nullptr, hb, nullptr);
        sage_mfma8<10><<<sage_blocks, 256, 0, stream>>>(hb, idx2, W2T, h2o, h2b, NUM_P, fo);
        temporal_mfma<<<temp_blocks, 256, 0, stream>>>(h2b, hist2, WhT, WTT, fo, nullptr, nullptr);
    } else {
        sage_v5<25, false><<<sage_blocks, 256, 0, stream>>>(feats, feats, idx1, W1, h1o, nullptr);
        temporal_v8<<<temp_blocks, 256, 0, stream>>>(h1o, hist1, Whis, WTm, fo, nullptr);
        sage_v5<10, true><<<sage_blocks, 256, 0, stream>>>(fo, h1o, idx2, W2, h2o, fo);
        temporal_v8<<<temp_blocks, 256, 0, stream>>>(h2o, hist2, Whis, WTm, fo, nullptr);
    }
}

// Round 17
// 117.062 us; speedup vs baseline: 1.5492x; 1.1335x over previous
//
#include <hip/hip_runtime.h>
#include <hip/hip_bf16.h>

#define N_NODES 50000
#define NUM_P   20000
#define D_DIM   128
#define ALPHA_  0.2f
#define EPS_    1e-12f
#define NT      16      // nodes per tile (50000 = 3125*16, 20000 = 1250*16)

typedef __attribute__((ext_vector_type(8))) short bf16x8;
typedef __attribute__((ext_vector_type(4))) float f32x4;
typedef __attribute__((ext_vector_type(2))) float f32x2;

#if defined(__has_builtin)
#if __has_builtin(__builtin_amdgcn_cvt_pk_f32_fp8) && __has_builtin(__builtin_amdgcn_cvt_pk_fp8_f32)
#define HAVE_HW_FP8 1
#endif
#endif

__device__ __forceinline__ float4 f4zero() { return make_float4(0.f, 0.f, 0.f, 0.f); }

__device__ __forceinline__ void scale4(float4& v, const float s) {
    v.x *= s; v.y *= s; v.z *= s; v.w *= s;
}

__device__ __forceinline__ short f2bf(float f) {
    __hip_bfloat16 h = __float2bfloat16(f);
    return *reinterpret_cast<short*>(&h);
}

__device__ __forceinline__ float bf2f(short u) {
    union { unsigned i; float f; } c;
    c.i = ((unsigned)(unsigned short)u) << 16;
    return c.f;
}

__device__ __forceinline__ short4 pack4(const float4 v) {
    short4 s;
    s.x = f2bf(v.x); s.y = f2bf(v.y); s.z = f2bf(v.z); s.w = f2bf(v.w);
    return s;
}

// ---------------- fp8 e4m3 helpers (HW cvt on gfx950, SW fallback) ----------
__device__ __forceinline__ float fp8_sw_dec(unsigned b) {
    unsigned e = (b >> 3) & 0xF, m = b & 7;
    float v = (e == 0) ? (float)m * 0.001953125f
                       : __uint_as_float(((e + 120u) << 23) | (m << 20));
    return (b & 0x80) ? -v : v;
}

__device__ __forceinline__ unsigned fp8_sw_enc(float f) {
    unsigned s = f < 0.f ? 0x80u : 0u;
    float af = fabsf(f);
    if (af >= 448.f) return s | 0x7E;
    if (af < 0.0009765625f) return s;
    int e; float m = frexpf(af, &e);
    int E = e - 1;
    if (E < -6) {
        int q = (int)rintf(af * 512.f);
        if (q >= 8) return s | 0x08;
        return s | (unsigned)q;
    }
    int q = (int)rintf(m * 16.f);
    if (q == 16) { q = 8; ++E; }
    if (E > 8) return s | 0x7E;
    return s | ((unsigned)(E + 7) << 3) | (unsigned)(q - 8);
}

template<bool HI>
__device__ __forceinline__ f32x2 fp8x2_dec(unsigned v) {
#ifdef HAVE_HW_FP8
    return __builtin_amdgcn_cvt_pk_f32_fp8((int)v, HI);
#else
    f32x2 r;
    unsigned b0 = HI ? ((v >> 16) & 0xFF) : (v & 0xFF);
    unsigned b1 = HI ? (v >> 24)          : ((v >> 8) & 0xFF);
    r[0] = fp8_sw_dec(b0); r[1] = fp8_sw_dec(b1);
    return r;
#endif
}

__device__ __forceinline__ unsigned char f2fp8(float v) {
#ifdef HAVE_HW_FP8
    return (unsigned char)(__builtin_amdgcn_cvt_pk_fp8_f32(v, v, 0, false) & 0xFF);
#else
    return (unsigned char)fp8_sw_enc(v);
#endif
}

__device__ __forceinline__ unsigned pack4_fp8(const float4 v) {
#ifdef HAVE_HW_FP8
    int lo = __builtin_amdgcn_cvt_pk_fp8_f32(v.x, v.y, 0, false);
    return (unsigned)__builtin_amdgcn_cvt_pk_fp8_f32(v.z, v.w, lo, true);
#else
    return fp8_sw_enc(v.x) | (fp8_sw_enc(v.y) << 8) |
           (fp8_sw_enc(v.z) << 16) | (fp8_sw_enc(v.w) << 24);
#endif
}

// ---------------------------------------------------------------------------
// Merged convert: blocks [0,448) transpose weights to bf16; blocks [448,...)
// mirror feats to bf16 + fp8.
// ---------------------------------------------------------------------------
__global__ __launch_bounds__(256)
void cvt_all_kernel(const float* __restrict__ W1, const float* __restrict__ W2,
                    const float* __restrict__ Whis, const float* __restrict__ WTm,
                    short* __restrict__ ow,
                    const float* __restrict__ feats, short* __restrict__ ob,
                    unsigned* __restrict__ o8)
{
    if (blockIdx.x < 448) {
        const int i = blockIdx.x * 256 + threadIdx.x;   // 0..114687
        float v;
        if (i < 65536) {
            const float* W = (i < 32768) ? W1 : W2;
            const int t = i & 32767;
            v = W[(size_t)(t & 255) * D_DIM + (t >> 8)];
        } else if (i < 81920) {
            const int t = i - 65536;
            v = Whis[(size_t)(t & 127) * D_DIM + (t >> 7)];
        } else {
            const int t = i - 81920;
            v = WTm[(size_t)(t & 255) * D_DIM + (t >> 8)];
        }
        ow[i] = f2bf(v);
    } else {
        const int i = (blockIdx.x - 448) * 256 + threadIdx.x;   // float4 index
        const float4 v = reinterpret_cast<const float4*>(feats)[i];
        reinterpret_cast<short4*>(ob)[i] = pack4(v);
        o8[i] = pack4_fp8(v);
    }
}

// fp32 -> bf16 mirror only (fallback path)
__global__ __launch_bounds__(256)
void fcvt_kernel(const float* __restrict__ in, short* __restrict__ ob)
{
    const int i = blockIdx.x * 256 + threadIdx.x;
    const float4 v = reinterpret_cast<const float4*>(in)[i];
    reinterpret_cast<short4*>(ob)[i] = pack4(v);
}

// ---------------------------------------------------------------------------
// Fused SAGE + temporal. Sage: h = l2norm(leaky([self | mean_k nb] @ W)).
// If hist != null and block covers rows < NUM_P, continue in-block with
// temporal: f = l2norm(leaky([h | (mean_p hist)@Whis] @ WT)).
// Outputs:
//   out0  fp32: sage result, ALL rows (h1o / h2o)
//   tail1 fp32: sage result, rows >= NUM_P (null / fo)
//   tb,t8 bf16/fp8 table: rows>=NUM_P sage result; rows<NUM_P temporal result
//   tout  fp32: temporal result rows < NUM_P (null / fo)
// ---------------------------------------------------------------------------
template<int K>
__global__ __launch_bounds__(256)
void sage_fused(const short*    __restrict__ srcB,
                const unsigned* __restrict__ src8,
                const int*      __restrict__ idx,
                const short*    __restrict__ WTg,      // [128][256] bf16
                const float*    __restrict__ hist,     // [3][NUM_P][128] fp32 (nullable)
                const short*    __restrict__ WhisTg,   // [128][128] bf16
                const short*    __restrict__ WTTg,     // [128][256] bf16
                float* __restrict__ out0,
                float* __restrict__ tail1,
                short* __restrict__ tb,
                unsigned char* __restrict__ t8,
                float* __restrict__ tout)
{
    __shared__ __align__(16) char uni[NT * 132 * 4];
    __shared__ float rnorm[NT];
    __shared__ int   sidx[NT * K];
    short* xs = reinterpret_cast<short*>(uni);   // [n][256] bf16, swizzled
    float* ys = reinterpret_cast<float*>(uni);   // [n][132] fp32

    const int tid  = threadIdx.x;
    const int base = blockIdx.x * NT;

    for (int i = tid; i < NT * K; i += 256)
        sidx[i] = idx[(size_t)base * K + i];
    __syncthreads();

    // ---- gather: 16 lanes per row; one node per 16-lane group ----
    {
        const int n = tid >> 4;
        const int l = tid & 15;
        const int node = base + n;
        const int swzn = (n & 7) << 3;

        const int4 s8 = reinterpret_cast<const int4*>(srcB + (size_t)node * D_DIM)[l];

        float a0 = 0.f, a1 = 0.f, a2 = 0.f, a3 = 0.f;
        float a4 = 0.f, a5 = 0.f, a6 = 0.f, a7 = 0.f;
        for (int k = 0; k < K; ++k) {
            const int r = sidx[n * K + k];
            const uint2 v = *reinterpret_cast<const uint2*>(src8 + (size_t)r * 32 + l * 2);
            const f32x2 p0 = fp8x2_dec<false>(v.x);
            const f32x2 p1 = fp8x2_dec<true>(v.x);
            const f32x2 p2 = fp8x2_dec<false>(v.y);
            const f32x2 p3 = fp8x2_dec<true>(v.y);
            a0 += p0[0]; a1 += p0[1]; a2 += p1[0]; a3 += p1[1];
            a4 += p2[0]; a5 += p2[1]; a6 += p3[0]; a7 += p3[1];
        }
        const float s = 1.0f / (float)K;
        short m8[8];
        m8[0] = f2bf(a0 * s); m8[1] = f2bf(a1 * s); m8[2] = f2bf(a2 * s); m8[3] = f2bf(a3 * s);
        m8[4] = f2bf(a4 * s); m8[5] = f2bf(a5 * s); m8[6] = f2bf(a6 * s); m8[7] = f2bf(a7 * s);

        *reinterpret_cast<int4*>(&xs[n * 256 + ((l * 8) ^ swzn)])         = s8;
        *reinterpret_cast<int4*>(&xs[n * 256 + ((D_DIM + l * 8) ^ swzn)]) = *reinterpret_cast<int4*>(m8);
    }
    __syncthreads();

    // ---- MFMA machinery (shared between sage and temporal phases) ----
    const int w    = tid >> 6;
    const int l    = tid & 63;
    const int arow = l & 15;
    const int kg   = l >> 4;
    const int swz  = (arow & 7) << 3;
    const int colbase = w * 32;

    // ---- sage GEMM: K=256 in 8 steps ----
    {
        f32x4 acc0 = {0.f, 0.f, 0.f, 0.f};
        f32x4 acc1 = {0.f, 0.f, 0.f, 0.f};
        const short* b0 = WTg + (size_t)(colbase + arow) * 256 + kg * 8;
        const short* b1 = b0 + 16 * 256;
        #pragma unroll
        for (int step = 0; step < 8; ++step) {
            const int aoff = arow * 256 + ((step * 32 + kg * 8) ^ swz);
            const bf16x8 av  = *reinterpret_cast<const bf16x8*>(&xs[aoff]);
            const bf16x8 bv0 = *reinterpret_cast<const bf16x8*>(b0 + step * 32);
            const bf16x8 bv1 = *reinterpret_cast<const bf16x8*>(b1 + step * 32);
            acc0 = __builtin_amdgcn_mfma_f32_16x16x32_bf16(av, bv0, acc0, 0, 0, 0);
            acc1 = __builtin_amdgcn_mfma_f32_16x16x32_bf16(av, bv1, acc1, 0, 0, 0);
        }
        __syncthreads();
        const int r0 = kg * 4;
        #pragma unroll
        for (int r = 0; r < 4; ++r) {
            float v0 = acc0[r]; v0 = v0 > 0.f ? v0 : ALPHA_ * v0;
            float v1 = acc1[r]; v1 = v1 > 0.f ? v1 : ALPHA_ * v1;
            ys[(r0 + r) * 132 + colbase + arow]      = v0;
            ys[(r0 + r) * 132 + colbase + 16 + arow] = v1;
        }
    }
    __syncthreads();

    {
        const int n  = tid >> 4;
        const int ll = tid & 15;
        float s = 0.f;
        #pragma unroll
        for (int jj = 0; jj < D_DIM; jj += 16) { const float t = ys[n * 132 + ll + jj]; s += t * t; }
        #pragma unroll
        for (int o = 8; o > 0; o >>= 1) s += __shfl_xor(s, o);
        if (ll == 0) rnorm[n] = 1.0f / fmaxf(sqrtf(s), EPS_);
    }
    __syncthreads();

    // ---- sage write phase (values kept in regs) ----
    const int j = tid & 127;
    const int g = tid >> 7;
    float vout[8];
    #pragma unroll
    for (int r = 0; r < 8; ++r) {
        const int n = g * 8 + r;
        vout[r] = ys[n * 132 + j] * rnorm[n];
    }
    #pragma unroll
    for (int r = 0; r < 8; ++r)
        out0[(size_t)(base + g * 8 + r) * D_DIM + j] = vout[r];

    const bool temp = (hist != nullptr) && (base < NUM_P);

    if (!temp) {
        // rows here are >= NUM_P whenever tail1/tb/t8 matter
        #pragma unroll
        for (int r = 0; r < 8; ++r) {
            const int node = base + g * 8 + r;
            const size_t o = (size_t)node * D_DIM + j;
            if (node >= NUM_P) {
                if (tail1 != nullptr) tail1[o] = vout[r];
                if (tb != nullptr) tb[o] = f2bf(vout[r]);
                if (t8 != nullptr) t8[o] = f2fp8(vout[r]);
            } else {
                if (tb != nullptr) tb[o] = f2bf(vout[r]);
                if (t8 != nullptr) t8[o] = f2fp8(vout[r]);
            }
        }
        return;
    }

    // ================= temporal phase (rows < NUM_P) =================
    __syncthreads();   // all ys reads complete before xs overwrite

    // head: bf16(v) into swizzled A layout (cols 0..127)
    #pragma unroll
    for (int r = 0; r < 8; ++r) {
        const int n = g * 8 + r;
        const int swzn = (n & 7) << 3;
        xs[n * 256 + (j ^ swzn)] = f2bf(vout[r]);
    }
    // hist mean into cols 128..255
    {
        const int gp = tid >> 5;
        const int ll = tid & 31;
        const size_t HS = (size_t)NUM_P * D_DIM;
        for (int n = gp; n < NT; n += 8) {
            const size_t off = (size_t)(base + n) * D_DIM;
            const float4 p0 = reinterpret_cast<const float4*>(hist + off)[ll];
            const float4 p1 = reinterpret_cast<const float4*>(hist + off + HS)[ll];
            const float4 p2 = reinterpret_cast<const float4*>(hist + off + 2 * HS)[ll];
            float4 m4;
            m4.x = (p0.x + p1.x + p2.x) * (1.0f / 3.0f);
            m4.y = (p0.y + p1.y + p2.y) * (1.0f / 3.0f);
            m4.z = (p0.z + p1.z + p2.z) * (1.0f / 3.0f);
            m4.w = (p0.w + p1.w + p2.w) * (1.0f / 3.0f);
            const int swzn = (n & 7) << 3;
            *reinterpret_cast<short4*>(&xs[n * 256 + ((D_DIM + ll * 4) ^ swzn)]) = pack4(m4);
        }
    }
    __syncthreads();

    // MFMA-A: tf = hm @ WhisT (K=128, 4 steps)
    {
        f32x4 t0 = {0.f, 0.f, 0.f, 0.f};
        f32x4 t1 = {0.f, 0.f, 0.f, 0.f};
        const short* b0 = WhisTg + (size_t)(colbase + arow) * 128 + kg * 8;
        const short* b1 = b0 + 16 * 128;
        #pragma unroll
        for (int step = 0; step < 4; ++step) {
            const int aoff = arow * 256 + ((D_DIM + step * 32 + kg * 8) ^ swz);
            const bf16x8 av  = *reinterpret_cast<const bf16x8*>(&xs[aoff]);
            const bf16x8 bv0 = *reinterpret_cast<const bf16x8*>(b0 + step * 32);
            const bf16x8 bv1 = *reinterpret_cast<const bf16x8*>(b1 + step * 32);
            t0 = __builtin_amdgcn_mfma_f32_16x16x32_bf16(av, bv0, t0, 0, 0, 0);
            t1 = __builtin_amdgcn_mfma_f32_16x16x32_bf16(av, bv1, t1, 0, 0, 0);
        }
        __syncthreads();
        #pragma unroll
        for (int r = 0; r < 4; ++r) {
            const int node = kg * 4 + r;
            const int swzn = (node & 7) << 3;
            xs[node * 256 + ((D_DIM + colbase + arow) ^ swzn)]      = f2bf(t0[r]);
            xs[node * 256 + ((D_DIM + colbase + 16 + arow) ^ swzn)] = f2bf(t1[r]);
        }
    }
    __syncthreads();

    // MFMA-B: y = [head | tf] @ WTT (K=256, 8 steps)
    {
        f32x4 acc0 = {0.f, 0.f, 0.f, 0.f};
        f32x4 acc1 = {0.f, 0.f, 0.f, 0.f};
        const short* b0 = WTTg + (size_t)(colbase + arow) * 256 + kg * 8;
        const short* b1 = b0 + 16 * 256;
        #pragma unroll
        for (int step = 0; step < 8; ++step) {
            const int aoff = arow * 256 + ((step * 32 + kg * 8) ^ swz);
            const bf16x8 av  = *reinterpret_cast<const bf16x8*>(&xs[aoff]);
            const bf16x8 bv0 = *reinterpret_cast<const bf16x8*>(b0 + step * 32);
            const bf16x8 bv1 = *reinterpret_cast<const bf16x8*>(b1 + step * 32);
            acc0 = __builtin_amdgcn_mfma_f32_16x16x32_bf16(av, bv0, acc0, 0, 0, 0);
            acc1 = __builtin_amdgcn_mfma_f32_16x16x32_bf16(av, bv1, acc1, 0, 0, 0);
        }
        __syncthreads();
        const int r0 = kg * 4;
        #pragma unroll
        for (int r = 0; r < 4; ++r) {
            float v0 = acc0[r]; v0 = v0 > 0.f ? v0 : ALPHA_ * v0;
            float v1 = acc1[r]; v1 = v1 > 0.f ? v1 : ALPHA_ * v1;
            ys[(r0 + r) * 132 + colbase + arow]      = v0;
            ys[(r0 + r) * 132 + colbase + 16 + arow] = v1;
        }
    }
    __syncthreads();

    {
        const int n  = tid >> 4;
        const int ll = tid & 15;
        float s = 0.f;
        #pragma unroll
        for (int jj = 0; jj < D_DIM; jj += 16) { const float t = ys[n * 132 + ll + jj]; s += t * t; }
        #pragma unroll
        for (int o = 8; o > 0; o >>= 1) s += __shfl_xor(s, o);
        if (ll == 0) rnorm[n] = 1.0f / fmaxf(sqrtf(s), EPS_);
    }
    __syncthreads();

    #pragma unroll
    for (int r = 0; r < 8; ++r) {
        const int n = g * 8 + r;
        const float v = ys[n * 132 + j] * rnorm[n];
        const size_t o = (size_t)(base + n) * D_DIM + j;
        if (tout != nullptr) tout[o] = v;
        if (tb != nullptr) tb[o] = f2bf(v);
        if (t8 != nullptr) t8[o] = f2fp8(v);
    }
}

// ---------------------------------------------------------------------------
// Standalone MFMA temporal (needA fallback). headb/outb may alias.
// ---------------------------------------------------------------------------
__global__ __launch_bounds__(256)
void temporal_mfma(const short* headb,
                   const float* __restrict__ hist,
                   const short* __restrict__ WhisTg,
                   const short* __restrict__ WTTg,
                   float* __restrict__ outp,
                   short* outb)
{
    __shared__ __align__(16) char uni[NT * 132 * 4];
    __shared__ float rnorm[NT];
    short* xs = reinterpret_cast<short*>(uni);
    float* ys = reinterpret_cast<float*>(uni);

    const int tid  = threadIdx.x;
    const int base = blockIdx.x * NT;
    const size_t HS = (size_t)NUM_P * D_DIM;

    {
        const int gp = tid >> 5;
        const int l  = tid & 31;
        for (int n = gp; n < NT; n += 8) {
            const size_t off = (size_t)(base + n) * D_DIM;
            const short4 h4 = reinterpret_cast<const short4*>(headb + off)[l];
            const float4 p0 = reinterpret_cast<const float4*>(hist + off)[l];
            const float4 p1 = reinterpret_cast<const float4*>(hist + off + HS)[l];
            const float4 p2 = reinterpret_cast<const float4*>(hist + off + 2 * HS)[l];
            float4 m4;
            m4.x = (p0.x + p1.x + p2.x) * (1.0f / 3.0f);
            m4.y = (p0.y + p1.y + p2.y) * (1.0f / 3.0f);
            m4.z = (p0.z + p1.z + p2.z) * (1.0f / 3.0f);
            m4.w = (p0.w + p1.w + p2.w) * (1.0f / 3.0f);
            const int swzn = (n & 7) << 3;
            *reinterpret_cast<short4*>(&xs[n * 256 + ((l * 4) ^ swzn)])         = h4;
            *reinterpret_cast<short4*>(&xs[n * 256 + ((D_DIM + l * 4) ^ swzn)]) = pack4(m4);
        }
    }
    __syncthreads();

    const int w    = tid >> 6;
    const int l    = tid & 63;
    const int arow = l & 15;
    const int kg   = l >> 4;
    const int swz  = (arow & 7) << 3;
    const int colbase = w * 32;

    {
        f32x4 t0 = {0.f, 0.f, 0.f, 0.f};
        f32x4 t1 = {0.f, 0.f, 0.f, 0.f};
        const short* b0 = WhisTg + (size_t)(colbase + arow) * 128 + kg * 8;
        const short* b1 = b0 + 16 * 128;
        #pragma unroll
        for (int step = 0; step < 4; ++step) {
            const int aoff = arow * 256 + ((D_DIM + step * 32 + kg * 8) ^ swz);
            const bf16x8 av  = *reinterpret_cast<const bf16x8*>(&xs[aoff]);
            const bf16x8 bv0 = *reinterpret_cast<const bf16x8*>(b0 + step * 32);
            const bf16x8 bv1 = *reinterpret_cast<const bf16x8*>(b1 + step * 32);
            t0 = __builtin_amdgcn_mfma_f32_16x16x32_bf16(av, bv0, t0, 0, 0, 0);
            t1 = __builtin_amdgcn_mfma_f32_16x16x32_bf16(av, bv1, t1, 0, 0, 0);
        }
        __syncthreads();
        #pragma unroll
        for (int r = 0; r < 4; ++r) {
            const int node = kg * 4 + r;
            const int swzn = (node & 7) << 3;
            xs[node * 256 + ((D_DIM + colbase + arow) ^ swzn)]      = f2bf(t0[r]);
            xs[node * 256 + ((D_DIM + colbase + 16 + arow) ^ swzn)] = f2bf(t1[r]);
        }
    }
    __syncthreads();

    f32x4 acc0 = {0.f, 0.f, 0.f, 0.f};
    f32x4 acc1 = {0.f, 0.f, 0.f, 0.f};
    {
        const short* b0 = WTTg + (size_t)(colbase + arow) * 256 + kg * 8;
        const short* b1 = b0 + 16 * 256;
        #pragma unroll
        for (int step = 0; step < 8; ++step) {
            const int aoff = arow * 256 + ((step * 32 + kg * 8) ^ swz);
            const bf16x8 av  = *reinterpret_cast<const bf16x8*>(&xs[aoff]);
            const bf16x8 bv0 = *reinterpret_cast<const bf16x8*>(b0 + step * 32);
            const bf16x8 bv1 = *reinterpret_cast<const bf16x8*>(b1 + step * 32);
            acc0 = __builtin_amdgcn_mfma_f32_16x16x32_bf16(av, bv0, acc0, 0, 0, 0);
            acc1 = __builtin_amdgcn_mfma_f32_16x16x32_bf16(av, bv1, acc1, 0, 0, 0);
        }
    }
    __syncthreads();

    {
        const int r0 = kg * 4;
        #pragma unroll
        for (int r = 0; r < 4; ++r) {
            float v0 = acc0[r]; v0 = v0 > 0.f ? v0 : ALPHA_ * v0;
            float v1 = acc1[r]; v1 = v1 > 0.f ? v1 : ALPHA_ * v1;
            ys[(r0 + r) * 132 + colbase + arow]      = v0;
            ys[(r0 + r) * 132 + colbase + 16 + arow] = v1;
        }
    }
    __syncthreads();

    {
        const int n  = tid >> 4;
        const int ll = tid & 15;
        float s = 0.f;
        #pragma unroll
        for (int jj = 0; jj < D_DIM; jj += 16) { const float t = ys[n * 132 + ll + jj]; s += t * t; }
        #pragma unroll
        for (int o = 8; o > 0; o >>= 1) s += __shfl_xor(s, o);
        if (ll == 0) rnorm[n] = 1.0f / fmaxf(sqrtf(s), EPS_);
    }
    __syncthreads();

    {
        const int j = tid & 127;
        const int g = tid >> 7;
        #pragma unroll
        for (int r = 0; r < 8; ++r) {
            const int n = g * 8 + r;
            const float v = ys[n * 132 + j] * rnorm[n];
            const size_t o = (size_t)(base + n) * D_DIM + j;
            if (outp != nullptr) outp[o] = v;
            if (outb != nullptr) outb[o] = f2bf(v);
        }
    }
}

// ---------------------------------------------------------------------------
// bf16-gather MFMA SAGE (needA fallback)
// ---------------------------------------------------------------------------
template<int K>
__global__ __launch_bounds__(256)
void sage_mfma8(const short* __restrict__ src,
                const int*   __restrict__ idx,
                const short* __restrict__ WTg,
                float* __restrict__ out0,
                short* __restrict__ outb,
                int nb_limit,
                float* __restrict__ out1)
{
    __shared__ __align__(16) char uni[NT * 132 * 4];
    __shared__ float rnorm[NT];
    __shared__ int   sidx[NT * K];
    short* xs = reinterpret_cast<short*>(uni);
    float* ys = reinterpret_cast<float*>(uni);

    const int tid  = threadIdx.x;
    const int base = blockIdx.x * NT;

    for (int i = tid; i < NT * K; i += 256)
        sidx[i] = idx[(size_t)base * K + i];
    __syncthreads();

    {
        const int gp = tid >> 5;
        const int l  = tid & 31;
        for (int n = gp; n < NT; n += 8) {
            const int node = base + n;
            const short4 s4 = reinterpret_cast<const short4*>(src + (size_t)node * D_DIM)[l];
            float4 a4 = f4zero();
            for (int k = 0; k < K; ++k) {
                const int r = sidx[n * K + k];
                const short4 v4 = reinterpret_cast<const short4*>(src + (size_t)r * D_DIM)[l];
                a4.x += bf2f(v4.x); a4.y += bf2f(v4.y);
                a4.z += bf2f(v4.z); a4.w += bf2f(v4.w);
            }
            scale4(a4, 1.0f / (float)K);
            const int swzn = (n & 7) << 3;
            *reinterpret_cast<short4*>(&xs[n * 256 + ((l * 4) ^ swzn)])         = s4;
            *reinterpret_cast<short4*>(&xs[n * 256 + ((D_DIM + l * 4) ^ swzn)]) = pack4(a4);
        }
    }
    __syncthreads();

    const int w    = tid >> 6;
    const int l    = tid & 63;
    const int arow = l & 15;
    const int kg   = l >> 4;
    const int swz  = (arow & 7) << 3;

    f32x4 acc0 = {0.f, 0.f, 0.f, 0.f};
    f32x4 acc1 = {0.f, 0.f, 0.f, 0.f};
    const int colbase = w * 32;
    const short* b0 = WTg + (size_t)(colbase + arow) * 256 + kg * 8;
    const short* b1 = b0 + 16 * 256;

    #pragma unroll
    for (int step = 0; step < 8; ++step) {
        const int aoff = arow * 256 + ((step * 32 + kg * 8) ^ swz);
        const bf16x8 av  = *reinterpret_cast<const bf16x8*>(&xs[aoff]);
        const bf16x8 bv0 = *reinterpret_cast<const bf16x8*>(b0 + step * 32);
        const bf16x8 bv1 = *reinterpret_cast<const bf16x8*>(b1 + step * 32);
        acc0 = __builtin_amdgcn_mfma_f32_16x16x32_bf16(av, bv0, acc0, 0, 0, 0);
        acc1 = __builtin_amdgcn_mfma_f32_16x16x32_bf16(av, bv1, acc1, 0, 0, 0);
    }
    __syncthreads();

    {
        const int r0 = kg * 4;
        #pragma unroll
        for (int r = 0; r < 4; ++r) {
            float v0 = acc0[r]; v0 = v0 > 0.f ? v0 : ALPHA_ * v0;
            float v1 = acc1[r]; v1 = v1 > 0.f ? v1 : ALPHA_ * v1;
            ys[(r0 + r) * 132 + colbase + arow]      = v0;
            ys[(r0 + r) * 132 + colbase + 16 + arow] = v1;
        }
    }
    __syncthreads();

    {
        const int n  = tid >> 4;
        const int ll = tid & 15;
        float s = 0.f;
        #pragma unroll
        for (int jj = 0; jj < D_DIM; jj += 16) { const float t = ys[n * 132 + ll + jj]; s += t * t; }
        #pragma unroll
        for (int o = 8; o > 0; o >>= 1) s += __shfl_xor(s, o);
        if (ll == 0) rnorm[n] = 1.0f / fmaxf(sqrtf(s), EPS_);
    }
    __syncthreads();

    {
        const int j = tid & 127;
        const int g = tid >> 7;
        #pragma unroll
        for (int r = 0; r < 8; ++r) {
            const int n    = g * 8 + r;
            const int node = base + n;
            const float v  = ys[n * 132 + j] * rnorm[n];
            out0[(size_t)node * D_DIM + j] = v;
            if (outb != nullptr && node < nb_limit) outb[(size_t)node * D_DIM + j] = f2bf(v);
            if (out1 != nullptr && node >= NUM_P)   out1[(size_t)node * D_DIM + j] = v;
        }
    }
}

// ---------------------------------------------------------------------------
// fp32 fallbacks (no/small workspace)
// ---------------------------------------------------------------------------
__global__ __launch_bounds__(256)
void temporal_v8(const float* __restrict__ head,
                 const float* __restrict__ hist,
                 const float* __restrict__ Whis,
                 const float* __restrict__ WTm,
                 float* __restrict__ outp,
                 short* __restrict__ outb)
{
    __shared__ float xs[NT][2 * D_DIM];
    __shared__ float hm[NT][D_DIM];
    __shared__ float rnorm[NT];

    const int tid  = threadIdx.x;
    const int base = blockIdx.x * NT;
    const size_t HS = (size_t)NUM_P * D_DIM;

    {
        const int gp = tid >> 5;
        const int l  = tid & 31;
        for (int n = gp; n < NT; n += 8) {
            const size_t off = (size_t)(base + n) * D_DIM;
            const float4 h4 = reinterpret_cast<const float4*>(head + off)[l];
            const float4 p0 = reinterpret_cast<const float4*>(hist + off)[l];
            const float4 p1 = reinterpret_cast<const float4*>(hist + off + HS)[l];
            const float4 p2 = reinterpret_cast<const float4*>(hist + off + 2 * HS)[l];
            float4 m4;
            m4.x = (p0.x + p1.x + p2.x) * (1.0f / 3.0f);
            m4.y = (p0.y + p1.y + p2.y) * (1.0f / 3.0f);
            m4.z = (p0.z + p1.z + p2.z) * (1.0f / 3.0f);
            m4.w = (p0.w + p1.w + p2.w) * (1.0f / 3.0f);
            reinterpret_cast<float4*>(&xs[n][0])[l] = h4;
            reinterpret_cast<float4*>(&hm[n][0])[l] = m4;
        }
    }
    __syncthreads();

    const int j  = tid & 127;
    const int g  = tid >> 7;
    const int nb = g * 8;

    {
        float a2[8];
        #pragma unroll
        for (int r = 0; r < 8; ++r) a2[r] = 0.f;
        for (int c4 = 0; c4 < D_DIM / 4; ++c4) {
            const int c = c4 * 4;
            const float w0 = Whis[(size_t)(c + 0) * D_DIM + j];
            const float w1 = Whis[(size_t)(c + 1) * D_DIM + j];
            const float w2 = Whis[(size_t)(c + 2) * D_DIM + j];
            const float w3 = Whis[(size_t)(c + 3) * D_DIM + j];
            #pragma unroll
            for (int r = 0; r < 8; ++r) {
                const float4 xv = *reinterpret_cast<const float4*>(&hm[nb + r][c]);
                a2[r] = fmaf(xv.w, w3, fmaf(xv.z, w2, fmaf(xv.y, w1, fmaf(xv.x, w0, a2[r]))));
            }
        }
        __syncthreads();
        #pragma unroll
        for (int r = 0; r < 8; ++r) xs[nb + r][D_DIM + j] = a2[r];
    }
    __syncthreads();

    float acc[8];
    #pragma unroll
    for (int r = 0; r < 8; ++r) acc[r] = 0.f;
    for (int c4 = 0; c4 < (2 * D_DIM) / 4; ++c4) {
        const int c = c4 * 4;
        const float w0 = WTm[(size_t)(c + 0) * D_DIM + j];
        const float w1 = WTm[(size_t)(c + 1) * D_DIM + j];
        const float w2 = WTm[(size_t)(c + 2) * D_DIM + j];
        const float w3 = WTm[(size_t)(c + 3) * D_DIM + j];
        #pragma unroll
        for (int r = 0; r < 8; ++r) {
            const float4 xv = *reinterpret_cast<const float4*>(&xs[nb + r][c]);
            acc[r] = fmaf(xv.w, w3, fmaf(xv.z, w2, fmaf(xv.y, w1, fmaf(xv.x, w0, acc[r]))));
        }
    }
    __syncthreads();

    #pragma unroll
    for (int r = 0; r < 8; ++r) {
        float v = acc[r];
        v = v > 0.f ? v : ALPHA_ * v;
        xs[nb + r][j] = v;
    }
    __syncthreads();

    {
        const int n  = tid >> 4;
        const int ll = tid & 15;
        float s = 0.f;
        #pragma unroll
        for (int jj = ll; jj < D_DIM; jj += 16) { const float t = xs[n][jj]; s += t * t; }
        #pragma unroll
        for (int o = 8; o > 0; o >>= 1) s += __shfl_xor(s, o);
        if (ll == 0) rnorm[n] = 1.0f / fmaxf(sqrtf(s), EPS_);
    }
    __syncthreads();

    #pragma unroll
    for (int r = 0; r < 8; ++r) {
        const int n = nb + r;
        const float v = xs[n][j] * rnorm[n];
        const size_t o = (size_t)(base + n) * D_DIM + j;
        if (outp != nullptr) outp[o] = v;
        if (outb != nullptr) outb[o] = f2bf(v);
    }
}

template<int K, bool SPLIT>
__global__ __launch_bounds__(256)
void sage_v5(const float* __restrict__ srcLow,
             const float* __restrict__ srcHigh,
             const int*   __restrict__ idx,
             const float* __restrict__ W,
             float* __restrict__ out0,
             float* __restrict__ out1)
{
    __shared__ float xs[NT][2 * D_DIM];
    __shared__ int   sidx[NT * K];
    __shared__ float rnorm[NT];

    const int tid  = threadIdx.x;
    const int base = blockIdx.x * NT;

    for (int i = tid; i < NT * K; i += 256)
        sidx[i] = idx[(size_t)base * K + i];
    __syncthreads();

    {
        const int gp = tid >> 5;
        const int l  = tid & 31;
        for (int n = gp; n < NT; n += 8) {
            const int node = base + n;
            const float* sp = (!SPLIT || node < NUM_P) ? srcLow : srcHigh;
            const float4 s4 = reinterpret_cast<const float4*>(sp + (size_t)node * D_DIM)[l];
            float4 a4 = f4zero();
            for (int k = 0; k < K; ++k) {
                const int r = sidx[n * K + k];
                const float* rp = (!SPLIT || r < NUM_P) ? srcLow : srcHigh;
                const float4 v4 = reinterpret_cast<const float4*>(rp + (size_t)r * D_DIM)[l];
                a4.x += v4.x; a4.y += v4.y; a4.z += v4.z; a4.w += v4.w;
            }
            scale4(a4, 1.0f / (float)K);
            reinterpret_cast<float4*>(&xs[n][0])[l]     = s4;
            reinterpret_cast<float4*>(&xs[n][D_DIM])[l] = a4;
        }
    }
    __syncthreads();

    const int j  = tid & 127;
    const int g  = tid >> 7;
    const int nb = g * 8;

    float acc[8];
    #pragma unroll
    for (int r = 0; r < 8; ++r) acc[r] = 0.f;
    for (int c4 = 0; c4 < (2 * D_DIM) / 4; ++c4) {
        const int c = c4 * 4;
        const float w0 = W[(size_t)(c + 0) * D_DIM + j];
        const float w1 = W[(size_t)(c + 1) * D_DIM + j];
        const float w2 = W[(size_t)(c + 2) * D_DIM + j];
        const float w3 = W[(size_t)(c + 3) * D_DIM + j];
        #pragma unroll
        for (int r = 0; r < 8; ++r) {
            const float4 xv = *reinterpret_cast<const float4*>(&xs[nb + r][c]);
            acc[r] = fmaf(xv.w, w3, fmaf(xv.z, w2, fmaf(xv.y, w1, fmaf(xv.x, w0, acc[r]))));
        }
    }
    __syncthreads();

    #pragma unroll
    for (int r = 0; r < 8; ++r) {
        float v = acc[r];
        v = v > 0.f ? v : ALPHA_ * v;
        xs[nb + r][j] = v;
    }
    __syncthreads();

    {
        const int n  = tid >> 4;
        const int ll = tid & 15;
        float s = 0.f;
        #pragma unroll
        for (int jj = ll; jj < D_DIM; jj += 16) { const float t = xs[n][jj]; s += t * t; }
        #pragma unroll
        for (int o = 8; o > 0; o >>= 1) s += __shfl_xor(s, o);
        if (ll == 0) rnorm[n] = 1.0f / fmaxf(sqrtf(s), EPS_);
    }
    __syncthreads();

    #pragma unroll
    for (int r = 0; r < 8; ++r) {
        const int n    = nb + r;
        const int node = base + n;
        const float v  = xs[n][j] * rnorm[n];
        out0[(size_t)node * D_DIM + j] = v;
        if (out1 != nullptr && node >= NUM_P) out1[(size_t)node * D_DIM + j] = v;
    }
}

// ---------------------------------------------------------------------------
extern "C" void kernel_launch(void* const* d_in, const int* in_sizes, int n_in,
                              void* d_out, int out_size, void* d_ws, size_t ws_size,
                              hipStream_t stream)
{
    (void)in_sizes; (void)n_in; (void)out_size;

    const float* feats = (const float*)d_in[0];
    const int*   idx1  = (const int*)  d_in[1];
    const int*   idx2  = (const int*)  d_in[2];
    const float* hist1 = (const float*)d_in[3];
    const float* hist2 = (const float*)d_in[4];
    const float* W1    = (const float*)d_in[5];
    const float* W2    = (const float*)d_in[6];
    const float* Whis  = (const float*)d_in[7];
    const float* WTm   = (const float*)d_in[8];

    float* out = (float*)d_out;
    float* h1o = out;
    float* h2o = out + (size_t)N_NODES * D_DIM;
    float* fo  = out + 2 * (size_t)N_NODES * D_DIM;

    const int sage_blocks = N_NODES / NT;  // 3125
    const int temp_blocks = NUM_P   / NT;  // 1250

    const size_t SZ_N  = (size_t)N_NODES * D_DIM;   // 6.4M elems
    const size_t SZ_P  = (size_t)NUM_P  * D_DIM;    // 2.56M elems
    const size_t WOFF  = 114688;                     // transposed weights (shorts)
    // layout: weights | fb(bf16 N) | hb(bf16 N) | h2b(bf16 NUM, unused in fused) | f8 | h8
    const size_t needF8 = (WOFF + 2 * SZ_N + SZ_P) * 2 + 2 * SZ_N;  // ~43.7 MB
    const size_t needA  = (WOFF + 2 * SZ_N + SZ_P) * 2;             // ~30.9 MB

    short* wsp  = (short*)d_ws;
    short* W1T  = wsp;
    short* W2T  = wsp + 32768;
    short* WhT  = wsp + 65536;
    short* WTT  = wsp + 81920;
    short* fb   = wsp + WOFF;                 // bf16 feats  [N,128]
    short* hb   = fb + SZ_N;                  // bf16 h1_copy [N,128]
    short* h2b  = hb + SZ_N;                  // bf16 h2 (fallback only)
    unsigned* f8 = (unsigned*)(h2b + SZ_P);   // fp8 feats  [N,128]
    unsigned* h8 = f8 + SZ_N / 4;             // fp8 h1_copy [N,128]

    if (ws_size >= needF8) {
        cvt_all_kernel<<<448 + (int)(SZ_N / 1024), 256, 0, stream>>>(
            W1, W2, Whis, WTm, wsp, feats, fb, f8);

        // fused sage1+temporal1: h1 -> h1o (all rows); table hb/h8:
        //   rows<NUM <- f1 (temporal), rows>=NUM <- h1
        sage_fused<25><<<sage_blocks, 256, 0, stream>>>(
            fb, f8, idx1, W1T, hist1, WhT, WTT,
            h1o, nullptr, hb, (unsigned char*)h8, nullptr);

        // fused sage2+temporal2: h2 -> h2o (all rows); fo tail <- h2 rows>=NUM;
        //   fo rows<NUM <- f2 (temporal)
        sage_fused<10><<<sage_blocks, 256, 0, stream>>>(
            hb, h8, idx2, W2T, hist2, WhT, WTT,
            h2o, fo, nullptr, nullptr, fo);
    } else if (ws_size >= needA) {
        cvt_all_kernel<<<448, 256, 0, stream>>>(W1, W2, Whis, WTm, wsp, feats, fb, f8);
        fcvt_kernel<<<(int)(SZ_N / 1024), 256, 0, stream>>>(feats, fb);

        sage_mfma8<25><<<sage_blocks, 256, 0, stream>>>(fb, idx1, W1T, h1o, hb, N_NODES, nullptr);
        temporal_mfma<<<temp_blocks, 256, 0, stream>>>(hb, hist1, WhT, WTT, nullptr, hb);
        sage_mfma8<10><<<sage_blocks, 256, 0, stream>>>(hb, idx2, W2T, h2o, h2b, NUM_P, fo);
        temporal_mfma<<<temp_blocks, 256, 0, stream>>>(h2b, hist2, WhT, WTT, fo, nullptr);
    } else {
        sage_v5<25, false><<<sage_blocks, 256, 0, stream>>>(feats, feats, idx1, W1, h1o, nullptr);
        temporal_v8<<<temp_blocks, 256, 0, stream>>>(h1o, hist1, Whis, WTm, fo, nullptr);
        sage_v5<10, true><<<sage_blocks, 256, 0, stream>>>(fo, h1o, idx2, W2, h2o, fo);
        temporal_v8<<<temp_blocks, 256, 0, stream>>>(h2o, hist2, Whis, WTm, fo, nullptr);
    }
}